// Round 12
// baseline (1006.412 us; speedup 1.0000x reference)
//
#include <hip/hip_runtime.h>
#include <math.h>

typedef __bf16 bf16x8 __attribute__((ext_vector_type(8)));
typedef float  f32x4  __attribute__((ext_vector_type(4)));

// ============================ constants ============================
constexpr int NPTS = 32768;
constexpr long long SOFF = 33554432LL;        // NPTS*64*16, start of scalar outputs

// ---- fp32 weight region (stage_a) in d_ws, float offsets ----
constexpr int OFF_GBW     = 0;        // [64c][3ch][128r][4]
constexpr int OFF_GB_S2MV = 98304;    // [32kq][128r][4]
constexpr int FP_TOTAL    = 114688;   // floats (448KB)

// ---- bf16 fragment region (bcdm), element offsets; hi at [0,TOT), lo at [TOT,2TOT) ----
constexpr int TOT_BF   = 323584;
constexpr int FB_MVB    = 0;        // [9k][4nt][2ks][64l][8e] = 36864
constexpr int FB_MVC    = 36864;
constexpr int FB_MVD    = 73728;
constexpr int FB_S2MV_B = 110592;   // [4nt][4ks][64][8] = 8192   (K=128)
constexpr int FB_S2MV_C = 118784;   // [4nt][8ks][64][8] = 16384  (K=256)
constexpr int FB_S2MV_D = 135168;   // 16384
constexpr int FB_S2S_B  = 151552;   // [16nt][4ks][64][8] = 32768
constexpr int FB_S2S_C  = 184320;   // [16nt][8ks][64][8] = 65536
constexpr int FB_S2S_D  = 249856;   // [8nt][8ks][64][8]  = 32768
constexpr int FB_MS2S_B = 282624;   // [16nt][2ks][64][8] = 16384
constexpr int FB_MS2S_C = 299008;   // 16384
constexpr int FB_MS2S_D = 315392;   // [8nt][2ks][64][8]  = 8192 -> 323584

// ---- bcdm LDS layout (bytes) ----
constexpr int XA_OFF  = 0;        // bf16 [16j][16p][64c] swizzled, 32768
constexpr int SA_OFF  = 32768;    // bf16 [16p][128] swizzled, 4096
constexpr int T1_OFF  = 36864;    // bf16 [16p][256] swizzled, 8192
constexpr int T2_OFF  = 45056;    // 8192
constexpr int C0_OFF  = 53248;    // bf16 [16p][64] swizzled, 2048
constexpr int GT_OFF  = 55296;    // f32 [16p][64o] gate, 4096
constexpr int RED_OFF = 59392;    // 3 x f32[8wv][16p] = 1536
constexpr int LDS_BYTES = 60928;

// ==================== compile-time GA tables (stage_a) ====================
namespace ga {
constexpr int MASK_OF[16] = {0,1,2,4,8,3,5,9,6,10,12,7,11,13,14,15};
constexpr int idx_of_mask(int m){ int r = 0; for(int i=0;i<16;++i) if(MASK_OF[i]==m) r=i; return r; }
constexpr int pcount(int x){ int c=0; while(x){ c += x&1; x >>= 1; } return c; }
constexpr int nswaps(int a,int b){ int s=0; a >>= 1; while(a){ s += pcount(a&b); a >>= 1; } return s; }
constexpr float rsign(int a,int b){ return (nswaps(a,b)&1) ? -1.0f : 1.0f; }
constexpr float dsign(int m){ return rsign(m, 15^m); }
struct Ent { int i, j, k; float s; };
struct GPT { Ent e[192]; };
constexpr GPT make_gp(){
  GPT t{}; int n=0;
  for(int i=0;i<16;++i) for(int j=0;j<16;++j){
    const int a=MASK_OF[i], b=MASK_OF[j];
    if((a & b & 1) != 0) continue;
    t.e[n].i=i; t.e[n].j=j; t.e[n].k=idx_of_mask(a^b); t.e[n].s=rsign(a,b); ++n;
  }
  return t;
}
struct JNT { Ent e[81]; };
constexpr JNT make_jn(){
  JNT t{}; int n=0;
  for(int i=0;i<16;++i) for(int j=0;j<16;++j){
    const int ci = 15 ^ MASK_OF[i], cj = 15 ^ MASK_OF[j];
    if((ci & cj) != 0) continue;
    const int mr = ci ^ cj, mk = 15 ^ mr;
    t.e[n].i=i; t.e[n].j=j; t.e[n].k=idx_of_mask(mk);
    t.e[n].s = dsign(MASK_OF[i]) * dsign(MASK_OF[j]) * rsign(ci,cj) * dsign(mk);
    ++n;
  }
  return t;
}
constexpr GPT GPt = make_gp();
constexpr JNT JNt = make_jn();
} // namespace ga

// ============================ helpers ============================
__device__ __forceinline__ float dot4(float4 a, float4 b){
  return fmaf(a.x,b.x, fmaf(a.y,b.y, fmaf(a.z,b.z, a.w*b.w)));
}
__device__ __forceinline__ float gelu_t(float x){
  const float u = 0.7978845608028654f * x * (1.0f + 0.044715f * x * x);
  return 0.5f * x * (1.0f + tanhf(u));
}
__device__ __forceinline__ void accum_equi(float* __restrict__ a,
                                           const float* __restrict__ w,
                                           const float* __restrict__ x){
  a[0]  = fmaf(w[0],x[0],a[0]);
  a[1]  = fmaf(w[1],x[1],fmaf(w[5],x[0],a[1]));
  a[2]  = fmaf(w[1],x[2],a[2]);
  a[3]  = fmaf(w[1],x[3],a[3]);
  a[4]  = fmaf(w[1],x[4],a[4]);
  a[5]  = fmaf(w[2],x[5],fmaf(w[6],x[2],a[5]));
  a[6]  = fmaf(w[2],x[6],fmaf(w[6],x[3],a[6]));
  a[7]  = fmaf(w[2],x[7],fmaf(w[6],x[4],a[7]));
  a[8]  = fmaf(w[2],x[8],a[8]);
  a[9]  = fmaf(w[2],x[9],a[9]);
  a[10] = fmaf(w[2],x[10],a[10]);
  a[11] = fmaf(w[3],x[11],fmaf(w[7],x[8],a[11]));
  a[12] = fmaf(w[3],x[12],fmaf(w[7],x[9],a[12]));
  a[13] = fmaf(w[3],x[13],fmaf(w[7],x[10],a[13]));
  a[14] = fmaf(w[3],x[14],a[14]);
  a[15] = fmaf(w[4],x[15],fmaf(w[8],x[14],a[15]));
}
__device__ __forceinline__ void ld16(const float* __restrict__ p, float* __restrict__ x){
  const float4 a=*(const float4*)p, b=*(const float4*)(p+4), c=*(const float4*)(p+8), d=*(const float4*)(p+12);
  x[0]=a.x; x[1]=a.y; x[2]=a.z; x[3]=a.w; x[4]=b.x; x[5]=b.y; x[6]=b.z; x[7]=b.w;
  x[8]=c.x; x[9]=c.y; x[10]=c.z; x[11]=c.w; x[12]=d.x; x[13]=d.y; x[14]=d.z; x[15]=d.w;
}
__device__ __forceinline__ void st16(float* __restrict__ p, const float* __restrict__ x){
  *(float4*)(p)    = make_float4(x[0],x[1],x[2],x[3]);
  *(float4*)(p+4)  = make_float4(x[4],x[5],x[6],x[7]);
  *(float4*)(p+8)  = make_float4(x[8],x[9],x[10],x[11]);
  *(float4*)(p+12) = make_float4(x[12],x[13],x[14],x[15]);
}
__device__ __forceinline__ int swz(int p, int byteoff){ return byteoff ^ ((p & 7) << 4); }

// ======================= prep: fp32 stage_a weights =======================
__global__ void prep_fp(const float* __restrict__ gb_w_mv,
                        const float* __restrict__ gb_w_s2mv,
                        float* __restrict__ W)
{
  const int idx = blockIdx.x * 256 + threadIdx.x;
  if (idx >= FP_TOTAL) return;
  float v = 0.0f;
  if (idx < OFF_GB_S2MV) {
    const int j=idx&3, t=idx>>2, r=t&127, t2=t>>7, ch=t2%3, c=t2/3, k=ch*4+j;
    if (k < 9) v = gb_w_mv[(r*64 + c)*9 + k];
  } else {
    const int l=idx-OFF_GB_S2MV, j=l&3, t=l>>2, r=t&127, kq=t>>7;
    v = gb_w_s2mv[r*128 + kq*4 + j];
  }
  W[idx] = v;
}

// ======================= prep: bf16 fragment weights (hi+lo) =======================
__global__ void prep_bf(
    const float* __restrict__ gbo_w_mv, const float* __restrict__ gbo_w_s2mv,
    const float* __restrict__ gbo_w_mvs2s, const float* __restrict__ gbo_w_s2s,
    const float* __restrict__ l1_w_mv, const float* __restrict__ l1_w_s2mv,
    const float* __restrict__ l1_w_mvs2s, const float* __restrict__ l1_w_s2s,
    const float* __restrict__ l2_w_mv, const float* __restrict__ l2_w_s2mv,
    const float* __restrict__ l2_w_mvs2s, const float* __restrict__ l2_w_s2s,
    unsigned short* __restrict__ WBu)
{
  const int idx = blockIdx.x * 256 + threadIdx.x;
  if (idx >= TOT_BF) return;
  float v = 0.0f;
  if (idx < FB_S2MV_B) {
    const int st = idx / 36864, r2 = idx % 36864;
    const int k9 = r2 >> 12, r3 = r2 & 4095;
    const int nt = r3 >> 10, ks = (r3 >> 9) & 1, l = (r3 >> 3) & 63, e = r3 & 7;
    const int o = 16*nt + (l & 15), c = 32*ks + 8*(l >> 4) + e;
    const float* src = st==0 ? gbo_w_mv : (st==1 ? l1_w_mv : l2_w_mv);
    v = src[(o*64 + c)*9 + k9];
  } else if (idx < FB_S2S_B) {
    const float* src; int r, KS, KK;
    if (idx < FB_S2MV_C)      { r = idx - FB_S2MV_B; KS=4; KK=128; src=gbo_w_s2mv; }
    else if (idx < FB_S2MV_D) { r = idx - FB_S2MV_C; KS=8; KK=256; src=l1_w_s2mv; }
    else                      { r = idx - FB_S2MV_D; KS=8; KK=256; src=l2_w_s2mv; }
    const int per = KS*512, nt = r / per, r3 = r % per;
    const int ks = r3 >> 9, l = (r3 >> 3) & 63, e = r3 & 7;
    const int o = 16*nt + (l & 15), k = 32*ks + 8*(l >> 4) + e;
    v = src[o*KK + k];
  } else if (idx < FB_MS2S_B) {
    const float* src; int r, KS, KK;
    if (idx < FB_S2S_C)      { r = idx - FB_S2S_B; KS=4; KK=128; src=gbo_w_s2s; }
    else if (idx < FB_S2S_D) { r = idx - FB_S2S_C; KS=8; KK=256; src=l1_w_s2s; }
    else                     { r = idx - FB_S2S_D; KS=8; KK=256; src=l2_w_s2s; }
    const int per = KS*512, nt = r / per, r3 = r % per;
    const int ks = r3 >> 9, l = (r3 >> 3) & 63, e = r3 & 7;
    const int o = 16*nt + (l & 15), k = 32*ks + 8*(l >> 4) + e;
    v = src[o*KK + k];
  } else {
    const float* src; int r;
    if (idx < FB_MS2S_C)      { r = idx - FB_MS2S_B; src = gbo_w_mvs2s; }
    else if (idx < FB_MS2S_D) { r = idx - FB_MS2S_C; src = l1_w_mvs2s; }
    else                      { r = idx - FB_MS2S_D; src = l2_w_mvs2s; }
    const int nt = r >> 10, r3 = r & 1023;
    const int ks = r3 >> 9, l = (r3 >> 3) & 63, e = r3 & 7;
    const int o = 16*nt + (l & 15), k = 32*ks + 8*(l >> 4) + e;
    v = src[o*64 + k];
  }
  __bf16* WB = (__bf16*)WBu;
  const __bf16 h = (__bf16)v;
  WB[idx] = h;
  WB[TOT_BF + idx] = (__bf16)(v - (float)h);
}

// ======================= Kernel A (unchanged) =======================
__global__ __launch_bounds__(256, 1) void stage_a(
    const float* __restrict__ xin, const float* __restrict__ sinp,
    const float* __restrict__ gb_b_mv, const float* __restrict__ W,
    float* __restrict__ hid)
{
  __shared__ float smem[16384];
  const int tid = threadIdx.x;
  const int n0  = blockIdx.x * 8;
  {
    const float4* src = (const float4*)(xin + (size_t)n0 * 1024);
    float4* dst = (float4*)smem;
    #pragma unroll
    for (int q = 0; q < 8; ++q) dst[q * 256 + tid] = src[q * 256 + tid];
    ((float4*)(smem + 8192))[tid] = ((const float4*)(sinp + (size_t)n0 * 128))[tid];
  }
  __syncthreads();
  const int r  = tid & 127;
  const int pg = tid >> 7;
  float acc[4][16];
  #pragma unroll
  for (int i = 0; i < 4; ++i)
    #pragma unroll
    for (int j = 0; j < 16; ++j) acc[i][j] = 0.0f;
  const float* Wg = W + OFF_GBW;
  const float* xp = smem + pg * 4096;
  for (int c = 0; c < 64; ++c) {
    const float4 wa = *(const float4*)(Wg + (((c*3+0)<<7) + r)*4);
    const float4 wb = *(const float4*)(Wg + (((c*3+1)<<7) + r)*4);
    const float4 wc = *(const float4*)(Wg + (((c*3+2)<<7) + r)*4);
    const float w12[12] = {wa.x,wa.y,wa.z,wa.w, wb.x,wb.y,wb.z,wb.w, wc.x,wc.y,wc.z,wc.w};
    #pragma unroll
    for (int i = 0; i < 4; ++i) {
      float xv[16];
      ld16(xp + i*1024 + c*16, xv);
      accum_equi(acc[i], w12, xv);
    }
  }
  {
    const float* Ws = W + OFF_GB_S2MV;
    const float* sp = smem + 8192 + pg * 512;
    for (int kq = 0; kq < 32; ++kq) {
      const float4 wq = *(const float4*)(Ws + ((kq<<7) + r)*4);
      #pragma unroll
      for (int i = 0; i < 4; ++i) {
        const float4 sv = *(const float4*)(sp + i*128 + (kq<<2));
        acc[i][0] += dot4(wq, sv);
      }
    }
    const float bias = gb_b_mv[r];
    #pragma unroll
    for (int i = 0; i < 4; ++i) acc[i][0] += bias;
  }
  __syncthreads();
  #pragma unroll
  for (int i = 0; i < 4; ++i)
    st16(smem + ((pg*4 + i)*128 + r)*16, acc[i]);
  __syncthreads();
  {
    const int h  = tid & 31;
    const int pp = tid >> 5;
    float L[16], R[16], o16[16];
    ld16(smem + (pp*128 + h)*16, L);
    ld16(smem + (pp*128 + 32 + h)*16, R);
    #pragma unroll
    for (int j = 0; j < 16; ++j) o16[j] = 0.0f;
    #pragma unroll
    for (int n = 0; n < 192; ++n)
      o16[ga::GPt.e[n].k] = fmaf(ga::GPt.e[n].s * L[ga::GPt.e[n].i], R[ga::GPt.e[n].j], o16[ga::GPt.e[n].k]);
    st16(hid + (((size_t)(n0 + pp) * 64) + h) * 16, o16);
    ld16(smem + (pp*128 + 64 + h)*16, L);
    ld16(smem + (pp*128 + 96 + h)*16, R);
    #pragma unroll
    for (int j = 0; j < 16; ++j) o16[j] = 0.0f;
    #pragma unroll
    for (int n = 0; n < 81; ++n)
      o16[ga::JNt.e[n].k] = fmaf(ga::JNt.e[n].s * L[ga::JNt.e[n].i], R[ga::JNt.e[n].j], o16[ga::JNt.e[n].k]);
    st16(hid + (((size_t)(n0 + pp) * 64) + 32 + h) * 16, o16);
  }
}

// ======================= bcdm device helpers =======================
// Half of the mv equi-linear: blades JH*8..JH*8+7. Per-half basis needs
// partition almost disjointly (only W2 shared).
template<int JH>
__device__ __forceinline__ void mv_half(f32x4 (&acc)[8], const __bf16* __restrict__ WB,
                                        const unsigned char* lds, int mvbase, int w, int lane)
{
  constexpr int GRa[2][8] = {{0,1,1,1,1,2,2,2},{2,2,2,3,3,3,3,4}};
  constexpr int PJa[2][8] = {{-1,0,-1,-1,-1,2,3,4},{-1,-1,-1,8,9,10,-1,14}};
  constexpr int KEa[2][8] = {{0,5,0,0,0,6,6,6},{0,0,0,7,7,7,0,8}};
  const int pa  = lane & 15;
  const int cb0 = (lane >> 4) << 4;
  const int wl8 = lane << 3;
  #pragma unroll
  for (int jl = 0; jl < 8; ++jl) {
    const int j = JH*8 + jl;
    #pragma unroll
    for (int ks = 0; ks < 2; ++ks) {
      bf16x8 a = *(const bf16x8*)(lds + XA_OFF + (((j<<4)+pa)<<7) + swz(pa, cb0 + (ks<<6)));
      const __bf16* bp = WB + mvbase + GRa[JH][jl]*4096 + (w<<10) + (ks<<9) + wl8;
      acc[jl] = __builtin_amdgcn_mfma_f32_16x16x32_bf16(a, *(const bf16x8*)bp, acc[jl], 0, 0, 0);
      acc[jl] = __builtin_amdgcn_mfma_f32_16x16x32_bf16(a, *(const bf16x8*)(bp + TOT_BF), acc[jl], 0, 0, 0);
    }
    if (PJa[JH][jl] >= 0) {
      #pragma unroll
      for (int ks = 0; ks < 2; ++ks) {
        bf16x8 a = *(const bf16x8*)(lds + XA_OFF + (((PJa[JH][jl]<<4)+pa)<<7) + swz(pa, cb0 + (ks<<6)));
        const __bf16* bp = WB + mvbase + KEa[JH][jl]*4096 + (w<<10) + (ks<<9) + wl8;
        acc[jl] = __builtin_amdgcn_mfma_f32_16x16x32_bf16(a, *(const bf16x8*)bp, acc[jl], 0, 0, 0);
        acc[jl] = __builtin_amdgcn_mfma_f32_16x16x32_bf16(a, *(const bf16x8*)(bp + TOT_BF), acc[jl], 0, 0, 0);
      }
    }
  }
}
template<int KS, int RSH>
__device__ __forceinline__ void s_gemm(f32x4& acc, const __bf16* __restrict__ WB,
                                       const unsigned char* lds, int abase, int wbase, int lane)
{
  const int pa  = lane & 15;
  const int cb0 = (lane >> 4) << 4;
  const int wl8 = lane << 3;
  #pragma unroll
  for (int ks = 0; ks < KS; ++ks) {
    bf16x8 a = *(const bf16x8*)(lds + abase + (pa << RSH) + swz(pa, cb0 + (ks << 6)));
    const __bf16* bp = WB + wbase + (ks << 9) + wl8;
    acc = __builtin_amdgcn_mfma_f32_16x16x32_bf16(a, *(const bf16x8*)bp, acc, 0, 0, 0);
    acc = __builtin_amdgcn_mfma_f32_16x16x32_bf16(a, *(const bf16x8*)(bp + TOT_BF), acc, 0, 0, 0);
  }
}

// ======================= bcdm v2: blade-halves x o-tiles, 8 waves =======================
// 512 thr / 16 pts. wave = (w = o-tile, jh = blade half). acc[8] f32x4 = 32 VGPR.
// launch_bounds(512,2) -> VGPR cap 128 -> 4 waves/SIMD band. LDS 59.5KB -> 2 blk/CU.
// VERIFY next round: WRITE_SIZE must stay ~1.6e5 KB (spill tripwire).
__global__ __launch_bounds__(512, 2) void bcdm(
    const float* __restrict__ sinp,
    const float* __restrict__ gbo_b_mv, const float* __restrict__ gbo_b_s,
    const float* __restrict__ l1_b_mv,  const float* __restrict__ l1_b_s,
    const float* __restrict__ l2_b_mv,  const float* __restrict__ l2_b_s,
    const unsigned short* __restrict__ WBu,
    float* __restrict__ out)
{
  __shared__ __align__(16) unsigned char lds[LDS_BYTES];
  const __bf16* WB = (const __bf16*)WBu;
  const int tid = threadIdx.x, lane = tid & 63, wv = tid >> 6;
  const int w = wv & 3, jh = wv >> 2;
  const int pg = lane >> 4, ol = lane & 15;
  const int n0 = blockIdx.x * 16;

  { // stage hidden -> XA bf16 [j][p][c] swizzled, + C0, + SA (sinp)
    const float4* hsrc = (const float4*)(out + (size_t)n0 * 1024);
    #pragma unroll
    for (int q = 0; q < 8; ++q) {
      const int i = q * 512 + tid;
      const float4 v = hsrc[i];
      const int p = i >> 8, c = (i >> 2) & 63, j0 = (i & 3) << 2;
      const float vv[4] = {v.x, v.y, v.z, v.w};
      #pragma unroll
      for (int t = 0; t < 4; ++t)
        *(__bf16*)(lds + XA_OFF + ((((j0 + t) << 4) + p) << 7) + swz(p, 2 * c)) = (__bf16)vv[t];
      if (j0 == 0)
        *(__bf16*)(lds + C0_OFF + (p << 7) + swz(p, 2 * c)) = (__bf16)v.x;
    }
    {
      const float4 v = ((const float4*)(sinp + (size_t)n0 * 128))[tid];
      const int p = tid >> 5, k0 = (tid & 31) << 2;
      const float vv[4] = {v.x, v.y, v.z, v.w};
      #pragma unroll
      for (int t = 0; t < 4; ++t)
        *(__bf16*)(lds + SA_OFF + (p << 8) + swz(p, 2 * (k0 + t))) = (__bf16)vv[t];
    }
  }
  __syncthreads();

  float* REDEQ = (float*)(lds + RED_OFF);        // [8][16]
  float* REDS  = REDEQ + 128;
  float* REDQ  = REDEQ + 256;
  float* GT    = (float*)(lds + GT_OFF);         // [16p][64o]

  // ================= stages B and C =================
  #pragma unroll 1
  for (int stage = 0; stage < 2; ++stage) {
    const int mvb   = stage == 0 ? FB_MVB    : FB_MVC;
    const int s2mvb = stage == 0 ? FB_S2MV_B : FB_S2MV_C;
    const int s2sb  = stage == 0 ? FB_S2S_B  : FB_S2S_C;
    const int ms2sb = stage == 0 ? FB_MS2S_B : FB_MS2S_C;
    const int sab   = stage == 0 ? SA_OFF    : T1_OFF;
    const int tdst  = stage == 0 ? T1_OFF    : T2_OFF;
    const float* b_mv = stage == 0 ? gbo_b_mv : l1_b_mv;
    const float* b_s  = stage == 0 ? gbo_b_s  : l1_b_s;
    const int nt0 = 4*w + 2*jh;                  // this wave's 2 s2s/ms2s tiles

    f32x4 acc[8], fac[2];
    #pragma unroll
    for (int j = 0; j < 8; ++j) acc[j] = f32x4{0.f,0.f,0.f,0.f};
    fac[0] = f32x4{0.f,0.f,0.f,0.f}; fac[1] = f32x4{0.f,0.f,0.f,0.f};

    if (jh == 0) mv_half<0>(acc, WB, lds, mvb, w, lane);
    else         mv_half<1>(acc, WB, lds, mvb, w, lane);

    if (stage == 0) {
      if (jh == 0) s_gemm<4,8>(acc[0], WB, lds, sab, s2mvb + w*2048, lane);
      #pragma unroll
      for (int i = 0; i < 2; ++i) {
        s_gemm<4,8>(fac[i], WB, lds, sab, s2sb + (nt0+i)*2048, lane);
        s_gemm<2,7>(fac[i], WB, lds, C0_OFF, ms2sb + (nt0+i)*1024, lane);
      }
    } else {
      if (jh == 0) s_gemm<8,9>(acc[0], WB, lds, sab, s2mvb + w*4096, lane);
      #pragma unroll
      for (int i = 0; i < 2; ++i) {
        s_gemm<8,9>(fac[i], WB, lds, sab, s2sb + (nt0+i)*4096, lane);
        s_gemm<2,7>(fac[i], WB, lds, C0_OFF, ms2sb + (nt0+i)*1024, lane);
      }
    }
    __syncthreads();                    // (1) all LDS reads of this stage done

    // biases
    if (jh == 0) {
      const float bm = b_mv[16*w + ol];
      #pragma unroll
      for (int r = 0; r < 4; ++r) acc[0][r] += bm;
    }
    #pragma unroll
    for (int i = 0; i < 2; ++i) {
      const float bs = b_s[16*(nt0+i) + ol];
      #pragma unroll
      for (int r = 0; r < 4; ++r) fac[i][r] += bs;
    }
    // norm partials: equi INNER = {0,2,3,4 | 8,9,10,14} -> local {0,2,3,4} / {0,1,2,6}
    float sq[4], sm[4], s2[4];
    #pragma unroll
    for (int r = 0; r < 4; ++r) {
      sq[r] = (jh == 0)
        ? acc[0][r]*acc[0][r] + acc[2][r]*acc[2][r] + acc[3][r]*acc[3][r] + acc[4][r]*acc[4][r]
        : acc[0][r]*acc[0][r] + acc[1][r]*acc[1][r] + acc[2][r]*acc[2][r] + acc[6][r]*acc[6][r];
      sm[r] = fac[0][r] + fac[1][r];
      s2[r] = fac[0][r]*fac[0][r] + fac[1][r]*fac[1][r];
    }
    #pragma unroll
    for (int m = 1; m < 16; m <<= 1) {
      #pragma unroll
      for (int r = 0; r < 4; ++r) {
        sq[r] += __shfl_xor(sq[r], m);
        sm[r] += __shfl_xor(sm[r], m);
        s2[r] += __shfl_xor(s2[r], m);
      }
    }
    if (ol == 0) {
      #pragma unroll
      for (int r = 0; r < 4; ++r) {
        const int p = pg*4 + r;
        REDEQ[wv*16 + p] = sq[r]; REDS[wv*16 + p] = sm[r]; REDQ[wv*16 + p] = s2[r];
      }
    }
    __syncthreads();                    // (2) red visible

    float rs[4], mu[4], rstd[4];
    #pragma unroll
    for (int r = 0; r < 4; ++r) {
      const int p = pg*4 + r;
      float te = 0.f, ts = 0.f, tq = 0.f;
      #pragma unroll
      for (int v2 = 0; v2 < 8; ++v2) { te += REDEQ[v2*16+p]; ts += REDS[v2*16+p]; tq += REDQ[v2*16+p]; }
      rs[r]   = 1.0f / sqrtf(fmaxf(te * (1.0f/64.0f), 0.01f));
      mu[r]   = ts * (1.0f/256.0f);
      rstd[r] = rsqrtf(tq * (1.0f/256.0f) - mu[r]*mu[r] + 1e-5f);
    }
    // scalar out -> T (bf16)
    #pragma unroll
    for (int i = 0; i < 2; ++i) {
      #pragma unroll
      for (int r = 0; r < 4; ++r) {
        const int p = pg*4 + r, op = 16*(nt0+i) + ol;
        *(__bf16*)(lds + tdst + (p << 9) + swz(p, 2*op)) =
            (__bf16)gelu_t((fac[i][r] - mu[r]) * rstd[r]);
      }
    }
    // gate (j0 lives in jh=0) + new C0
    if (jh == 0) {
      const int cnew = 16*w + ol;
      #pragma unroll
      for (int r = 0; r < 4; ++r) {
        const int p = pg*4 + r;
        const float a0n = acc[0][r] * rs[r];
        const float g   = gelu_t(a0n);
        GT[p*64 + cnew] = g;
        *(__bf16*)(lds + C0_OFF + (p<<7) + swz(p, 2*cnew)) = (__bf16)(g * a0n);
      }
    }
    __syncthreads();                    // (3) gate visible

    { // gated mv -> XA (each wave writes its 8 blades)
      const int cnew = 16*w + ol;
      float f[4];
      #pragma unroll
      for (int r = 0; r < 4; ++r) f[r] = rs[r] * GT[(pg*4+r)*64 + cnew];
      #pragma unroll
      for (int jl = 0; jl < 8; ++jl) {
        const int j = jh*8 + jl;
        #pragma unroll
        for (int r = 0; r < 4; ++r) {
          const int p = pg*4 + r;
          *(__bf16*)(lds + XA_OFF + (((j<<4)+p)<<7) + swz(p, 2*cnew)) = (__bf16)(acc[jl][r] * f[r]);
        }
      }
    }
    __syncthreads();                    // (4) XA ready for next stage
  }

  // ================= stage D =================
  {
    f32x4 acc[8], fac2;
    #pragma unroll
    for (int j = 0; j < 8; ++j) acc[j] = f32x4{0.f,0.f,0.f,0.f};
    fac2 = f32x4{0.f,0.f,0.f,0.f};

    if (jh == 0) mv_half<0>(acc, WB, lds, FB_MVD, w, lane);
    else         mv_half<1>(acc, WB, lds, FB_MVD, w, lane);
    if (jh == 0) s_gemm<8,9>(acc[0], WB, lds, T2_OFF, FB_S2MV_D + w*4096, lane);
    const int ntd = w + 4*jh;           // 8 scalar tiles across 8 waves
    s_gemm<8,9>(fac2, WB, lds, T2_OFF, FB_S2S_D + ntd*4096, lane);
    s_gemm<2,7>(fac2, WB, lds, C0_OFF, FB_MS2S_D + ntd*1024, lane);

    if (jh == 0) {
      const float bm = l2_b_mv[16*w + ol];
      #pragma unroll
      for (int r = 0; r < 4; ++r) acc[0][r] += bm;
    }
    #pragma unroll
    for (int r = 0; r < 4; ++r) {
      const int p = pg*4 + r;
      float* dst = out + ((size_t)(n0 + p)*64 + 16*w + ol)*16 + jh*8;
      *(float4*)(dst+0) = make_float4(acc[0][r], acc[1][r], acc[2][r], acc[3][r]);
      *(float4*)(dst+4) = make_float4(acc[4][r], acc[5][r], acc[6][r], acc[7][r]);
    }
    {
      const int od = 16*ntd + ol;
      const float bs = l2_b_s[od];
      #pragma unroll
      for (int r = 0; r < 4; ++r) {
        const int p = pg*4 + r;
        out[SOFF + (size_t)(n0 + p)*128 + od] = fac2[r] + bs;
      }
    }
  }
}

// ============================ host launch ============================
extern "C" void kernel_launch(void* const* d_in, const int* in_sizes, int n_in,
                              void* d_out, int out_size, void* d_ws, size_t ws_size,
                              hipStream_t stream) {
  const float* xin          = (const float*)d_in[0];
  const float* sinp         = (const float*)d_in[1];
  const float* gb_w_mv      = (const float*)d_in[2];
  const float* gb_w_s2mv    = (const float*)d_in[3];
  const float* gb_b_mv      = (const float*)d_in[4];
  const float* gbo_w_mv     = (const float*)d_in[5];
  const float* gbo_w_s2mv   = (const float*)d_in[6];
  const float* gbo_b_mv     = (const float*)d_in[7];
  const float* gbo_w_mvs2s  = (const float*)d_in[8];
  const float* gbo_w_s2s    = (const float*)d_in[9];
  const float* gbo_b_s      = (const float*)d_in[10];
  const float* l1_w_mv      = (const float*)d_in[11];
  const float* l1_w_s2mv    = (const float*)d_in[12];
  const float* l1_b_mv      = (const float*)d_in[13];
  const float* l1_w_mvs2s   = (const float*)d_in[14];
  const float* l1_w_s2s     = (const float*)d_in[15];
  const float* l1_b_s       = (const float*)d_in[16];
  const float* l2_w_mv      = (const float*)d_in[17];
  const float* l2_w_s2mv    = (const float*)d_in[18];
  const float* l2_b_mv      = (const float*)d_in[19];
  const float* l2_w_mvs2s   = (const float*)d_in[20];
  const float* l2_w_s2s     = (const float*)d_in[21];
  const float* l2_b_s       = (const float*)d_in[22];
  float* W   = (float*)d_ws;
  unsigned short* WBu = (unsigned short*)(W + FP_TOTAL);
  float* out = (float*)d_out;

  prep_fp<<<(FP_TOTAL + 255) / 256, 256, 0, stream>>>(gb_w_mv, gb_w_s2mv, W);

  prep_bf<<<(TOT_BF + 255) / 256, 256, 0, stream>>>(
      gbo_w_mv, gbo_w_s2mv, gbo_w_mvs2s, gbo_w_s2s,
      l1_w_mv, l1_w_s2mv, l1_w_mvs2s, l1_w_s2s,
      l2_w_mv, l2_w_s2mv, l2_w_mvs2s, l2_w_s2s, WBu);

  stage_a<<<NPTS / 8, 256, 0, stream>>>(xin, sinp, gb_b_mv, W, out);

  bcdm<<<NPTS / 16, 512, 0, stream>>>(
      sinp, gbo_b_mv, gbo_b_s, l1_b_mv, l1_b_s, l2_b_mv, l2_b_s, WBu, out);
}

// Round 13
// 746.188 us; speedup vs baseline: 1.3487x; 1.3487x over previous
//
#include <hip/hip_runtime.h>
#include <math.h>

typedef __bf16 bf16x8 __attribute__((ext_vector_type(8)));
typedef float  f32x4  __attribute__((ext_vector_type(4)));

// ============================ constants ============================
constexpr int NPTS = 32768;
constexpr long long SOFF = 33554432LL;        // NPTS*64*16, start of scalar outputs

// ---- fp32 weight region (stage_a) in d_ws, float offsets ----
constexpr int OFF_GBW     = 0;        // [64c][3ch][128r][4]
constexpr int OFF_GB_S2MV = 98304;    // [32kq][128r][4]
constexpr int FP_TOTAL    = 114688;   // floats (448KB)

// ---- bf16 fragment region (bcdm), element offsets; hi at [0,TOT), lo at [TOT,2TOT) ----
constexpr int TOT_BF   = 323584;
constexpr int FB_MVB    = 0;        // [9k][4nt][2ks][64l][8e] = 36864
constexpr int FB_MVC    = 36864;
constexpr int FB_MVD    = 73728;
constexpr int FB_S2MV_B = 110592;   // [4nt][4ks][64][8] = 8192   (K=128)
constexpr int FB_S2MV_C = 118784;   // [4nt][8ks][64][8] = 16384  (K=256)
constexpr int FB_S2MV_D = 135168;   // 16384
constexpr int FB_S2S_B  = 151552;   // [16nt][4ks][64][8] = 32768
constexpr int FB_S2S_C  = 184320;   // [16nt][8ks][64][8] = 65536
constexpr int FB_S2S_D  = 249856;   // [8nt][8ks][64][8]  = 32768
constexpr int FB_MS2S_B = 282624;   // [16nt][2ks][64][8] = 16384
constexpr int FB_MS2S_C = 299008;   // 16384
constexpr int FB_MS2S_D = 315392;   // [8nt][2ks][64][8]  = 8192 -> 323584

// ---- bcdm LDS layout (bytes) ----
constexpr int XA_OFF  = 0;        // bf16 [16j][16p][64c] swizzled, 32768
constexpr int SA_OFF  = 32768;    // bf16 [16p][128] swizzled, 4096
constexpr int T1_OFF  = 36864;    // bf16 [16p][256] swizzled, 8192
constexpr int T2_OFF  = 45056;    // 8192
constexpr int C0_OFF  = 53248;    // bf16 [16p][64] swizzled, 2048
constexpr int GT_OFF  = 55296;    // f32 [16p][64o] gate, 4096
constexpr int RED_OFF = 59392;    // 3 x f32[8wv][16p] = 1536
constexpr int LDS_BYTES = 60928;

// ==================== compile-time GA tables (stage_a) ====================
namespace ga {
constexpr int MASK_OF[16] = {0,1,2,4,8,3,5,9,6,10,12,7,11,13,14,15};
constexpr int idx_of_mask(int m){ int r = 0; for(int i=0;i<16;++i) if(MASK_OF[i]==m) r=i; return r; }
constexpr int pcount(int x){ int c=0; while(x){ c += x&1; x >>= 1; } return c; }
constexpr int nswaps(int a,int b){ int s=0; a >>= 1; while(a){ s += pcount(a&b); a >>= 1; } return s; }
constexpr float rsign(int a,int b){ return (nswaps(a,b)&1) ? -1.0f : 1.0f; }
constexpr float dsign(int m){ return rsign(m, 15^m); }
struct Ent { int i, j, k; float s; };
struct GPT { Ent e[192]; };
constexpr GPT make_gp(){
  GPT t{}; int n=0;
  for(int i=0;i<16;++i) for(int j=0;j<16;++j){
    const int a=MASK_OF[i], b=MASK_OF[j];
    if((a & b & 1) != 0) continue;
    t.e[n].i=i; t.e[n].j=j; t.e[n].k=idx_of_mask(a^b); t.e[n].s=rsign(a,b); ++n;
  }
  return t;
}
struct JNT { Ent e[81]; };
constexpr JNT make_jn(){
  JNT t{}; int n=0;
  for(int i=0;i<16;++i) for(int j=0;j<16;++j){
    const int ci = 15 ^ MASK_OF[i], cj = 15 ^ MASK_OF[j];
    if((ci & cj) != 0) continue;
    const int mr = ci ^ cj, mk = 15 ^ mr;
    t.e[n].i=i; t.e[n].j=j; t.e[n].k=idx_of_mask(mk);
    t.e[n].s = dsign(MASK_OF[i]) * dsign(MASK_OF[j]) * rsign(ci,cj) * dsign(mk);
    ++n;
  }
  return t;
}
constexpr GPT GPt = make_gp();
constexpr JNT JNt = make_jn();
} // namespace ga

// ============================ helpers ============================
__device__ __forceinline__ float dot4(float4 a, float4 b){
  return fmaf(a.x,b.x, fmaf(a.y,b.y, fmaf(a.z,b.z, a.w*b.w)));
}
__device__ __forceinline__ float gelu_t(float x){
  const float u = 0.7978845608028654f * x * (1.0f + 0.044715f * x * x);
  return 0.5f * x * (1.0f + tanhf(u));
}
__device__ __forceinline__ void accum_equi(float* __restrict__ a,
                                           const float* __restrict__ w,
                                           const float* __restrict__ x){
  a[0]  = fmaf(w[0],x[0],a[0]);
  a[1]  = fmaf(w[1],x[1],fmaf(w[5],x[0],a[1]));
  a[2]  = fmaf(w[1],x[2],a[2]);
  a[3]  = fmaf(w[1],x[3],a[3]);
  a[4]  = fmaf(w[1],x[4],a[4]);
  a[5]  = fmaf(w[2],x[5],fmaf(w[6],x[2],a[5]));
  a[6]  = fmaf(w[2],x[6],fmaf(w[6],x[3],a[6]));
  a[7]  = fmaf(w[2],x[7],fmaf(w[6],x[4],a[7]));
  a[8]  = fmaf(w[2],x[8],a[8]);
  a[9]  = fmaf(w[2],x[9],a[9]);
  a[10] = fmaf(w[2],x[10],a[10]);
  a[11] = fmaf(w[3],x[11],fmaf(w[7],x[8],a[11]));
  a[12] = fmaf(w[3],x[12],fmaf(w[7],x[9],a[12]));
  a[13] = fmaf(w[3],x[13],fmaf(w[7],x[10],a[13]));
  a[14] = fmaf(w[3],x[14],a[14]);
  a[15] = fmaf(w[4],x[15],fmaf(w[8],x[14],a[15]));
}
__device__ __forceinline__ void ld16(const float* __restrict__ p, float* __restrict__ x){
  const float4 a=*(const float4*)p, b=*(const float4*)(p+4), c=*(const float4*)(p+8), d=*(const float4*)(p+12);
  x[0]=a.x; x[1]=a.y; x[2]=a.z; x[3]=a.w; x[4]=b.x; x[5]=b.y; x[6]=b.z; x[7]=b.w;
  x[8]=c.x; x[9]=c.y; x[10]=c.z; x[11]=c.w; x[12]=d.x; x[13]=d.y; x[14]=d.z; x[15]=d.w;
}
__device__ __forceinline__ void st16(float* __restrict__ p, const float* __restrict__ x){
  *(float4*)(p)    = make_float4(x[0],x[1],x[2],x[3]);
  *(float4*)(p+4)  = make_float4(x[4],x[5],x[6],x[7]);
  *(float4*)(p+8)  = make_float4(x[8],x[9],x[10],x[11]);
  *(float4*)(p+12) = make_float4(x[12],x[13],x[14],x[15]);
}
__device__ __forceinline__ int swz(int p, int byteoff){ return byteoff ^ ((p & 7) << 4); }

// ======================= prep: fp32 stage_a weights =======================
__global__ void prep_fp(const float* __restrict__ gb_w_mv,
                        const float* __restrict__ gb_w_s2mv,
                        float* __restrict__ W)
{
  const int idx = blockIdx.x * 256 + threadIdx.x;
  if (idx >= FP_TOTAL) return;
  float v = 0.0f;
  if (idx < OFF_GB_S2MV) {
    const int j=idx&3, t=idx>>2, r=t&127, t2=t>>7, ch=t2%3, c=t2/3, k=ch*4+j;
    if (k < 9) v = gb_w_mv[(r*64 + c)*9 + k];
  } else {
    const int l=idx-OFF_GB_S2MV, j=l&3, t=l>>2, r=t&127, kq=t>>7;
    v = gb_w_s2mv[r*128 + kq*4 + j];
  }
  W[idx] = v;
}

// ======================= prep: bf16 fragment weights =======================
// Fragment layout per matrix: [nt][ks][lane][8e], element (o = 16*nt + (l&15),
// k = 32*ks + 8*(l>>4) + e). B-operand of mfma_f32_16x16x32_bf16.
// lo region still written (unused this round) -- re-enable if absmax regresses.
__global__ void prep_bf(
    const float* __restrict__ gbo_w_mv, const float* __restrict__ gbo_w_s2mv,
    const float* __restrict__ gbo_w_mvs2s, const float* __restrict__ gbo_w_s2s,
    const float* __restrict__ l1_w_mv, const float* __restrict__ l1_w_s2mv,
    const float* __restrict__ l1_w_mvs2s, const float* __restrict__ l1_w_s2s,
    const float* __restrict__ l2_w_mv, const float* __restrict__ l2_w_s2mv,
    const float* __restrict__ l2_w_mvs2s, const float* __restrict__ l2_w_s2s,
    unsigned short* __restrict__ WBu)
{
  const int idx = blockIdx.x * 256 + threadIdx.x;
  if (idx >= TOT_BF) return;
  float v = 0.0f;
  if (idx < FB_S2MV_B) {
    const int st = idx / 36864, r2 = idx % 36864;
    const int k9 = r2 >> 12, r3 = r2 & 4095;
    const int nt = r3 >> 10, ks = (r3 >> 9) & 1, l = (r3 >> 3) & 63, e = r3 & 7;
    const int o = 16*nt + (l & 15), c = 32*ks + 8*(l >> 4) + e;
    const float* src = st==0 ? gbo_w_mv : (st==1 ? l1_w_mv : l2_w_mv);
    v = src[(o*64 + c)*9 + k9];
  } else if (idx < FB_S2S_B) {
    const float* src; int r, KS, KK;
    if (idx < FB_S2MV_C)      { r = idx - FB_S2MV_B; KS=4; KK=128; src=gbo_w_s2mv; }
    else if (idx < FB_S2MV_D) { r = idx - FB_S2MV_C; KS=8; KK=256; src=l1_w_s2mv; }
    else                      { r = idx - FB_S2MV_D; KS=8; KK=256; src=l2_w_s2mv; }
    const int per = KS*512, nt = r / per, r3 = r % per;
    const int ks = r3 >> 9, l = (r3 >> 3) & 63, e = r3 & 7;
    const int o = 16*nt + (l & 15), k = 32*ks + 8*(l >> 4) + e;
    v = src[o*KK + k];
  } else if (idx < FB_MS2S_B) {
    const float* src; int r, KS, KK;
    if (idx < FB_S2S_C)      { r = idx - FB_S2S_B; KS=4; KK=128; src=gbo_w_s2s; }
    else if (idx < FB_S2S_D) { r = idx - FB_S2S_C; KS=8; KK=256; src=l1_w_s2s; }
    else                     { r = idx - FB_S2S_D; KS=8; KK=256; src=l2_w_s2s; }
    const int per = KS*512, nt = r / per, r3 = r % per;
    const int ks = r3 >> 9, l = (r3 >> 3) & 63, e = r3 & 7;
    const int o = 16*nt + (l & 15), k = 32*ks + 8*(l >> 4) + e;
    v = src[o*KK + k];
  } else {
    const float* src; int r;
    if (idx < FB_MS2S_C)      { r = idx - FB_MS2S_B; src = gbo_w_mvs2s; }
    else if (idx < FB_MS2S_D) { r = idx - FB_MS2S_C; src = l1_w_mvs2s; }
    else                      { r = idx - FB_MS2S_D; src = l2_w_mvs2s; }
    const int nt = r >> 10, r3 = r & 1023;
    const int ks = r3 >> 9, l = (r3 >> 3) & 63, e = r3 & 7;
    const int o = 16*nt + (l & 15), k = 32*ks + 8*(l >> 4) + e;
    v = src[o*64 + k];
  }
  __bf16* WB = (__bf16*)WBu;
  const __bf16 h = (__bf16)v;
  WB[idx] = h;
  WB[TOT_BF + idx] = (__bf16)(v - (float)h);
}

// ======================= Kernel A (unchanged) =======================
__global__ __launch_bounds__(256, 1) void stage_a(
    const float* __restrict__ xin, const float* __restrict__ sinp,
    const float* __restrict__ gb_b_mv, const float* __restrict__ W,
    float* __restrict__ hid)
{
  __shared__ float smem[16384];
  const int tid = threadIdx.x;
  const int n0  = blockIdx.x * 8;
  {
    const float4* src = (const float4*)(xin + (size_t)n0 * 1024);
    float4* dst = (float4*)smem;
    #pragma unroll
    for (int q = 0; q < 8; ++q) dst[q * 256 + tid] = src[q * 256 + tid];
    ((float4*)(smem + 8192))[tid] = ((const float4*)(sinp + (size_t)n0 * 128))[tid];
  }
  __syncthreads();
  const int r  = tid & 127;
  const int pg = tid >> 7;
  float acc[4][16];
  #pragma unroll
  for (int i = 0; i < 4; ++i)
    #pragma unroll
    for (int j = 0; j < 16; ++j) acc[i][j] = 0.0f;
  const float* Wg = W + OFF_GBW;
  const float* xp = smem + pg * 4096;
  for (int c = 0; c < 64; ++c) {
    const float4 wa = *(const float4*)(Wg + (((c*3+0)<<7) + r)*4);
    const float4 wb = *(const float4*)(Wg + (((c*3+1)<<7) + r)*4);
    const float4 wc = *(const float4*)(Wg + (((c*3+2)<<7) + r)*4);
    const float w12[12] = {wa.x,wa.y,wa.z,wa.w, wb.x,wb.y,wb.z,wb.w, wc.x,wc.y,wc.z,wc.w};
    #pragma unroll
    for (int i = 0; i < 4; ++i) {
      float xv[16];
      ld16(xp + i*1024 + c*16, xv);
      accum_equi(acc[i], w12, xv);
    }
  }
  {
    const float* Ws = W + OFF_GB_S2MV;
    const float* sp = smem + 8192 + pg * 512;
    for (int kq = 0; kq < 32; ++kq) {
      const float4 wq = *(const float4*)(Ws + ((kq<<7) + r)*4);
      #pragma unroll
      for (int i = 0; i < 4; ++i) {
        const float4 sv = *(const float4*)(sp + i*128 + (kq<<2));
        acc[i][0] += dot4(wq, sv);
      }
    }
    const float bias = gb_b_mv[r];
    #pragma unroll
    for (int i = 0; i < 4; ++i) acc[i][0] += bias;
  }
  __syncthreads();
  #pragma unroll
  for (int i = 0; i < 4; ++i)
    st16(smem + ((pg*4 + i)*128 + r)*16, acc[i]);
  __syncthreads();
  {
    const int h  = tid & 31;
    const int pp = tid >> 5;
    float L[16], R[16], o16[16];
    ld16(smem + (pp*128 + h)*16, L);
    ld16(smem + (pp*128 + 32 + h)*16, R);
    #pragma unroll
    for (int j = 0; j < 16; ++j) o16[j] = 0.0f;
    #pragma unroll
    for (int n = 0; n < 192; ++n)
      o16[ga::GPt.e[n].k] = fmaf(ga::GPt.e[n].s * L[ga::GPt.e[n].i], R[ga::GPt.e[n].j], o16[ga::GPt.e[n].k]);
    st16(hid + (((size_t)(n0 + pp) * 64) + h) * 16, o16);
    ld16(smem + (pp*128 + 64 + h)*16, L);
    ld16(smem + (pp*128 + 96 + h)*16, R);
    #pragma unroll
    for (int j = 0; j < 16; ++j) o16[j] = 0.0f;
    #pragma unroll
    for (int n = 0; n < 81; ++n)
      o16[ga::JNt.e[n].k] = fmaf(ga::JNt.e[n].s * L[ga::JNt.e[n].i], R[ga::JNt.e[n].j], o16[ga::JNt.e[n].k]);
    st16(hid + (((size_t)(n0 + pp) * 64) + 32 + h) * 16, o16);
  }
}

// ======================= bcdm device helpers (hi-only MFMA) =======================
template<int JH>
__device__ __forceinline__ void mv_half(f32x4 (&acc)[8], const __bf16* __restrict__ WB,
                                        const unsigned char* lds, int mvbase, int w, int lane)
{
  constexpr int GRa[2][8] = {{0,1,1,1,1,2,2,2},{2,2,2,3,3,3,3,4}};
  constexpr int PJa[2][8] = {{-1,0,-1,-1,-1,2,3,4},{-1,-1,-1,8,9,10,-1,14}};
  constexpr int KEa[2][8] = {{0,5,0,0,0,6,6,6},{0,0,0,7,7,7,0,8}};
  const int pa  = lane & 15;
  const int cb0 = (lane >> 4) << 4;
  const int wl8 = lane << 3;
  #pragma unroll
  for (int jl = 0; jl < 8; ++jl) {
    const int j = JH*8 + jl;
    #pragma unroll
    for (int ks = 0; ks < 2; ++ks) {
      bf16x8 a = *(const bf16x8*)(lds + XA_OFF + (((j<<4)+pa)<<7) + swz(pa, cb0 + (ks<<6)));
      const __bf16* bp = WB + mvbase + GRa[JH][jl]*4096 + (w<<10) + (ks<<9) + wl8;
      acc[jl] = __builtin_amdgcn_mfma_f32_16x16x32_bf16(a, *(const bf16x8*)bp, acc[jl], 0, 0, 0);
    }
    if (PJa[JH][jl] >= 0) {
      #pragma unroll
      for (int ks = 0; ks < 2; ++ks) {
        bf16x8 a = *(const bf16x8*)(lds + XA_OFF + (((PJa[JH][jl]<<4)+pa)<<7) + swz(pa, cb0 + (ks<<6)));
        const __bf16* bp = WB + mvbase + KEa[JH][jl]*4096 + (w<<10) + (ks<<9) + wl8;
        acc[jl] = __builtin_amdgcn_mfma_f32_16x16x32_bf16(a, *(const bf16x8*)bp, acc[jl], 0, 0, 0);
      }
    }
  }
}
template<int KS, int RSH>
__device__ __forceinline__ void s_gemm(f32x4& acc, const __bf16* __restrict__ WB,
                                       const unsigned char* lds, int abase, int wbase, int lane)
{
  const int pa  = lane & 15;
  const int cb0 = (lane >> 4) << 4;
  const int wl8 = lane << 3;
  #pragma unroll
  for (int ks = 0; ks < KS; ++ks) {
    bf16x8 a = *(const bf16x8*)(lds + abase + (pa << RSH) + swz(pa, cb0 + (ks << 6)));
    const __bf16* bp = WB + wbase + (ks << 9) + wl8;
    acc = __builtin_amdgcn_mfma_f32_16x16x32_bf16(a, *(const bf16x8*)bp, acc, 0, 0, 0);
  }
}

// ======================= bcdm v3: (512,1) + hi-only =======================
// R12 post-mortem: (512,2) cap 128 < demand ~150 -> spill (WRITE 762MB).
// v3: cap 256 (no spill possible at ~150 demand) + hi-only MFMA (halves the
// latency-bound B-fragment load chain). Spill tripwire: WRITE must be ~1.6e5 KB.
__global__ __launch_bounds__(512, 1) void bcdm(
    const float* __restrict__ sinp,
    const float* __restrict__ gbo_b_mv, const float* __restrict__ gbo_b_s,
    const float* __restrict__ l1_b_mv,  const float* __restrict__ l1_b_s,
    const float* __restrict__ l2_b_mv,  const float* __restrict__ l2_b_s,
    const unsigned short* __restrict__ WBu,
    float* __restrict__ out)
{
  __shared__ __align__(16) unsigned char lds[LDS_BYTES];
  const __bf16* WB = (const __bf16*)WBu;
  const int tid = threadIdx.x, lane = tid & 63, wv = tid >> 6;
  const int w = wv & 3, jh = wv >> 2;
  const int pg = lane >> 4, ol = lane & 15;
  const int n0 = blockIdx.x * 16;

  { // stage hidden -> XA bf16 [j][p][c] swizzled, + C0, + SA (sinp)
    const float4* hsrc = (const float4*)(out + (size_t)n0 * 1024);
    #pragma unroll
    for (int q = 0; q < 8; ++q) {
      const int i = q * 512 + tid;
      const float4 v = hsrc[i];
      const int p = i >> 8, c = (i >> 2) & 63, j0 = (i & 3) << 2;
      const float vv[4] = {v.x, v.y, v.z, v.w};
      #pragma unroll
      for (int t = 0; t < 4; ++t)
        *(__bf16*)(lds + XA_OFF + ((((j0 + t) << 4) + p) << 7) + swz(p, 2 * c)) = (__bf16)vv[t];
      if (j0 == 0)
        *(__bf16*)(lds + C0_OFF + (p << 7) + swz(p, 2 * c)) = (__bf16)v.x;
    }
    {
      const float4 v = ((const float4*)(sinp + (size_t)n0 * 128))[tid];
      const int p = tid >> 5, k0 = (tid & 31) << 2;
      const float vv[4] = {v.x, v.y, v.z, v.w};
      #pragma unroll
      for (int t = 0; t < 4; ++t)
        *(__bf16*)(lds + SA_OFF + (p << 8) + swz(p, 2 * (k0 + t))) = (__bf16)vv[t];
    }
  }
  __syncthreads();

  float* REDEQ = (float*)(lds + RED_OFF);        // [8][16]
  float* REDS  = REDEQ + 128;
  float* REDQ  = REDEQ + 256;
  float* GT    = (float*)(lds + GT_OFF);         // [16p][64o]

  // ================= stages B and C =================
  #pragma unroll 1
  for (int stage = 0; stage < 2; ++stage) {
    const int mvb   = stage == 0 ? FB_MVB    : FB_MVC;
    const int s2mvb = stage == 0 ? FB_S2MV_B : FB_S2MV_C;
    const int s2sb  = stage == 0 ? FB_S2S_B  : FB_S2S_C;
    const int ms2sb = stage == 0 ? FB_MS2S_B : FB_MS2S_C;
    const int sab   = stage == 0 ? SA_OFF    : T1_OFF;
    const int tdst  = stage == 0 ? T1_OFF    : T2_OFF;
    const float* b_mv = stage == 0 ? gbo_b_mv : l1_b_mv;
    const float* b_s  = stage == 0 ? gbo_b_s  : l1_b_s;
    const int nt0 = 4*w + 2*jh;                  // this wave's 2 s2s/ms2s tiles

    f32x4 acc[8], fac[2];
    #pragma unroll
    for (int j = 0; j < 8; ++j) acc[j] = f32x4{0.f,0.f,0.f,0.f};
    fac[0] = f32x4{0.f,0.f,0.f,0.f}; fac[1] = f32x4{0.f,0.f,0.f,0.f};

    if (jh == 0) mv_half<0>(acc, WB, lds, mvb, w, lane);
    else         mv_half<1>(acc, WB, lds, mvb, w, lane);

    if (stage == 0) {
      if (jh == 0) s_gemm<4,8>(acc[0], WB, lds, sab, s2mvb + w*2048, lane);
      #pragma unroll
      for (int i = 0; i < 2; ++i) {
        s_gemm<4,8>(fac[i], WB, lds, sab, s2sb + (nt0+i)*2048, lane);
        s_gemm<2,7>(fac[i], WB, lds, C0_OFF, ms2sb + (nt0+i)*1024, lane);
      }
    } else {
      if (jh == 0) s_gemm<8,9>(acc[0], WB, lds, sab, s2mvb + w*4096, lane);
      #pragma unroll
      for (int i = 0; i < 2; ++i) {
        s_gemm<8,9>(fac[i], WB, lds, sab, s2sb + (nt0+i)*4096, lane);
        s_gemm<2,7>(fac[i], WB, lds, C0_OFF, ms2sb + (nt0+i)*1024, lane);
      }
    }
    __syncthreads();                    // (1) all LDS reads of this stage done

    // biases
    if (jh == 0) {
      const float bm = b_mv[16*w + ol];
      #pragma unroll
      for (int r = 0; r < 4; ++r) acc[0][r] += bm;
    }
    #pragma unroll
    for (int i = 0; i < 2; ++i) {
      const float bs = b_s[16*(nt0+i) + ol];
      #pragma unroll
      for (int r = 0; r < 4; ++r) fac[i][r] += bs;
    }
    // norm partials: equi INNER = {0,2,3,4 | 8,9,10,14} -> local {0,2,3,4} / {0,1,2,6}
    float sq[4], sm[4], s2[4];
    #pragma unroll
    for (int r = 0; r < 4; ++r) {
      sq[r] = (jh == 0)
        ? acc[0][r]*acc[0][r] + acc[2][r]*acc[2][r] + acc[3][r]*acc[3][r] + acc[4][r]*acc[4][r]
        : acc[0][r]*acc[0][r] + acc[1][r]*acc[1][r] + acc[2][r]*acc[2][r] + acc[6][r]*acc[6][r];
      sm[r] = fac[0][r] + fac[1][r];
      s2[r] = fac[0][r]*fac[0][r] + fac[1][r]*fac[1][r];
    }
    #pragma unroll
    for (int m = 1; m < 16; m <<= 1) {
      #pragma unroll
      for (int r = 0; r < 4; ++r) {
        sq[r] += __shfl_xor(sq[r], m);
        sm[r] += __shfl_xor(sm[r], m);
        s2[r] += __shfl_xor(s2[r], m);
      }
    }
    if (ol == 0) {
      #pragma unroll
      for (int r = 0; r < 4; ++r) {
        const int p = pg*4 + r;
        REDEQ[wv*16 + p] = sq[r]; REDS[wv*16 + p] = sm[r]; REDQ[wv*16 + p] = s2[r];
      }
    }
    __syncthreads();                    // (2) red visible

    float rs[4], mu[4], rstd[4];
    #pragma unroll
    for (int r = 0; r < 4; ++r) {
      const int p = pg*4 + r;
      float te = 0.f, ts = 0.f, tq = 0.f;
      #pragma unroll
      for (int v2 = 0; v2 < 8; ++v2) { te += REDEQ[v2*16+p]; ts += REDS[v2*16+p]; tq += REDQ[v2*16+p]; }
      rs[r]   = 1.0f / sqrtf(fmaxf(te * (1.0f/64.0f), 0.01f));
      mu[r]   = ts * (1.0f/256.0f);
      rstd[r] = rsqrtf(tq * (1.0f/256.0f) - mu[r]*mu[r] + 1e-5f);
    }
    // scalar out -> T (bf16)
    #pragma unroll
    for (int i = 0; i < 2; ++i) {
      #pragma unroll
      for (int r = 0; r < 4; ++r) {
        const int p = pg*4 + r, op = 16*(nt0+i) + ol;
        *(__bf16*)(lds + tdst + (p << 9) + swz(p, 2*op)) =
            (__bf16)gelu_t((fac[i][r] - mu[r]) * rstd[r]);
      }
    }
    // gate (j0 lives in jh=0) + new C0
    if (jh == 0) {
      const int cnew = 16*w + ol;
      #pragma unroll
      for (int r = 0; r < 4; ++r) {
        const int p = pg*4 + r;
        const float a0n = acc[0][r] * rs[r];
        const float g   = gelu_t(a0n);
        GT[p*64 + cnew] = g;
        *(__bf16*)(lds + C0_OFF + (p<<7) + swz(p, 2*cnew)) = (__bf16)(g * a0n);
      }
    }
    __syncthreads();                    // (3) gate visible

    { // gated mv -> XA (each wave writes its 8 blades)
      const int cnew = 16*w + ol;
      float f[4];
      #pragma unroll
      for (int r = 0; r < 4; ++r) f[r] = rs[r] * GT[(pg*4+r)*64 + cnew];
      #pragma unroll
      for (int jl = 0; jl < 8; ++jl) {
        const int j = jh*8 + jl;
        #pragma unroll
        for (int r = 0; r < 4; ++r) {
          const int p = pg*4 + r;
          *(__bf16*)(lds + XA_OFF + (((j<<4)+p)<<7) + swz(p, 2*cnew)) = (__bf16)(acc[jl][r] * f[r]);
        }
      }
    }
    __syncthreads();                    // (4) XA ready for next stage
  }

  // ================= stage D =================
  {
    f32x4 acc[8], fac2;
    #pragma unroll
    for (int j = 0; j < 8; ++j) acc[j] = f32x4{0.f,0.f,0.f,0.f};
    fac2 = f32x4{0.f,0.f,0.f,0.f};

    if (jh == 0) mv_half<0>(acc, WB, lds, FB_MVD, w, lane);
    else         mv_half<1>(acc, WB, lds, FB_MVD, w, lane);
    if (jh == 0) s_gemm<8,9>(acc[0], WB, lds, T2_OFF, FB_S2MV_D + w*4096, lane);
    const int ntd = w + 4*jh;           // 8 scalar tiles across 8 waves
    s_gemm<8,9>(fac2, WB, lds, T2_OFF, FB_S2S_D + ntd*4096, lane);
    s_gemm<2,7>(fac2, WB, lds, C0_OFF, FB_MS2S_D + ntd*1024, lane);

    if (jh == 0) {
      const float bm = l2_b_mv[16*w + ol];
      #pragma unroll
      for (int r = 0; r < 4; ++r) acc[0][r] += bm;
    }
    #pragma unroll
    for (int r = 0; r < 4; ++r) {
      const int p = pg*4 + r;
      float* dst = out + ((size_t)(n0 + p)*64 + 16*w + ol)*16 + jh*8;
      *(float4*)(dst+0) = make_float4(acc[0][r], acc[1][r], acc[2][r], acc[3][r]);
      *(float4*)(dst+4) = make_float4(acc[4][r], acc[5][r], acc[6][r], acc[7][r]);
    }
    {
      const int od = 16*ntd + ol;
      const float bs = l2_b_s[od];
      #pragma unroll
      for (int r = 0; r < 4; ++r) {
        const int p = pg*4 + r;
        out[SOFF + (size_t)(n0 + p)*128 + od] = fac2[r] + bs;
      }
    }
  }
}

// ============================ host launch ============================
extern "C" void kernel_launch(void* const* d_in, const int* in_sizes, int n_in,
                              void* d_out, int out_size, void* d_ws, size_t ws_size,
                              hipStream_t stream) {
  const float* xin          = (const float*)d_in[0];
  const float* sinp         = (const float*)d_in[1];
  const float* gb_w_mv      = (const float*)d_in[2];
  const float* gb_w_s2mv    = (const float*)d_in[3];
  const float* gb_b_mv      = (const float*)d_in[4];
  const float* gbo_w_mv     = (const float*)d_in[5];
  const float* gbo_w_s2mv   = (const float*)d_in[6];
  const float* gbo_b_mv     = (const float*)d_in[7];
  const float* gbo_w_mvs2s  = (const float*)d_in[8];
  const float* gbo_w_s2s    = (const float*)d_in[9];
  const float* gbo_b_s      = (const float*)d_in[10];
  const float* l1_w_mv      = (const float*)d_in[11];
  const float* l1_w_s2mv    = (const float*)d_in[12];
  const float* l1_b_mv      = (const float*)d_in[13];
  const float* l1_w_mvs2s   = (const float*)d_in[14];
  const float* l1_w_s2s     = (const float*)d_in[15];
  const float* l1_b_s       = (const float*)d_in[16];
  const float* l2_w_mv      = (const float*)d_in[17];
  const float* l2_w_s2mv    = (const float*)d_in[18];
  const float* l2_b_mv      = (const float*)d_in[19];
  const float* l2_w_mvs2s   = (const float*)d_in[20];
  const float* l2_w_s2s     = (const float*)d_in[21];
  const float* l2_b_s       = (const float*)d_in[22];
  float* W   = (float*)d_ws;
  unsigned short* WBu = (unsigned short*)(W + FP_TOTAL);
  float* out = (float*)d_out;

  prep_fp<<<(FP_TOTAL + 255) / 256, 256, 0, stream>>>(gb_w_mv, gb_w_s2mv, W);

  prep_bf<<<(TOT_BF + 255) / 256, 256, 0, stream>>>(
      gbo_w_mv, gbo_w_s2mv, gbo_w_mvs2s, gbo_w_s2s,
      l1_w_mv, l1_w_s2mv, l1_w_mvs2s, l1_w_s2s,
      l2_w_mv, l2_w_s2mv, l2_w_mvs2s, l2_w_s2s, WBu);

  stage_a<<<NPTS / 8, 256, 0, stream>>>(xin, sinp, gb_b_mv, W, out);

  bcdm<<<NPTS / 16, 512, 0, stream>>>(
      sinp, gbo_b_mv, gbo_b_s, l1_b_mv, l1_b_s, l2_b_mv, l2_b_s, WBu, out);
}

// Round 15
// 466.905 us; speedup vs baseline: 2.1555x; 1.5982x over previous
//
#include <hip/hip_runtime.h>
#include <math.h>

typedef __bf16 bf16x8 __attribute__((ext_vector_type(8)));
typedef float  f32x4  __attribute__((ext_vector_type(4)));

// ============================ constants ============================
constexpr int NPTS = 32768;
constexpr long long SOFF = 33554432LL;        // NPTS*64*16, start of scalar outputs

// ---- bf16 fragment region (all weights), element offsets in WBu ----
// bcdm frags: hi at [0,TOT_BF), lo at [TOT_BF, 2*TOT_BF)
constexpr int TOT_BF   = 323584;
constexpr int FB_MVB    = 0;        // [9k][4nt][2ks][64l][8e] = 36864
constexpr int FB_MVC    = 36864;
constexpr int FB_MVD    = 73728;
constexpr int FB_S2MV_B = 110592;   // [4nt][4ks][64][8] = 8192   (K=128)
constexpr int FB_S2MV_C = 118784;   // [4nt][8ks][64][8] = 16384  (K=256)
constexpr int FB_S2MV_D = 135168;   // 16384
constexpr int FB_S2S_B  = 151552;   // [16nt][4ks][64][8] = 32768
constexpr int FB_S2S_C  = 184320;   // [16nt][8ks][64][8] = 65536
constexpr int FB_S2S_D  = 249856;   // [8nt][8ks][64][8]  = 32768
constexpr int FB_MS2S_B = 282624;   // [16nt][2ks][64][8] = 16384
constexpr int FB_MS2S_C = 299008;   // 16384
constexpr int FB_MS2S_D = 315392;   // [8nt][2ks][64][8]  = 8192 -> 323584
// stage-A frags: hi at [SAW, SAW+SA_TOT), lo at [SAW+SA_TOT, SAW+2*SA_TOT)
constexpr int SAW      = 647168;    // = 2*TOT_BF
constexpr int GAS2_OFF = 73728;     // [8nt][4ks][64l][8e] = 16384
constexpr int SA_TOT   = 90112;     // ws usage = (SAW + 2*SA_TOT)*2B ~ 1.65MB

// ---- bcdm LDS layout (bytes) ----
constexpr int XA_OFF  = 0;        // bf16 [16j][16p][64c] swizzled, 32768
constexpr int SA_OFF  = 32768;    // bf16 [16p][128] swizzled, 4096
constexpr int T1_OFF  = 36864;    // bf16 [16p][256] swizzled, 8192
constexpr int T2_OFF  = 45056;    // 8192
constexpr int C0_OFF  = 53248;    // bf16 [16p][64] swizzled, 2048
constexpr int GT_OFF  = 55296;    // f32 [16p][64o] gate, 4096
constexpr int RED_OFF = 59392;    // 3 x f32[8wv][16p] = 1536
constexpr int LDS_BYTES = 60928;

// ==================== compile-time GA tables (GP/JOIN) ====================
namespace ga {
constexpr int MASK_OF[16] = {0,1,2,4,8,3,5,9,6,10,12,7,11,13,14,15};
constexpr int idx_of_mask(int m){ int r = 0; for(int i=0;i<16;++i) if(MASK_OF[i]==m) r=i; return r; }
constexpr int pcount(int x){ int c=0; while(x){ c += x&1; x >>= 1; } return c; }
constexpr int nswaps(int a,int b){ int s=0; a >>= 1; while(a){ s += pcount(a&b); a >>= 1; } return s; }
constexpr float rsign(int a,int b){ return (nswaps(a,b)&1) ? -1.0f : 1.0f; }
constexpr float dsign(int m){ return rsign(m, 15^m); }
struct Ent { int i, j, k; float s; };
struct GPT { Ent e[192]; };
constexpr GPT make_gp(){
  GPT t{}; int n=0;
  for(int i=0;i<16;++i) for(int j=0;j<16;++j){
    const int a=MASK_OF[i], b=MASK_OF[j];
    if((a & b & 1) != 0) continue;
    t.e[n].i=i; t.e[n].j=j; t.e[n].k=idx_of_mask(a^b); t.e[n].s=rsign(a,b); ++n;
  }
  return t;
}
struct JNT { Ent e[81]; };
constexpr JNT make_jn(){
  JNT t{}; int n=0;
  for(int i=0;i<16;++i) for(int j=0;j<16;++j){
    const int ci = 15 ^ MASK_OF[i], cj = 15 ^ MASK_OF[j];
    if((ci & cj) != 0) continue;
    const int mr = ci ^ cj, mk = 15 ^ mr;
    t.e[n].i=i; t.e[n].j=j; t.e[n].k=idx_of_mask(mk);
    t.e[n].s = dsign(MASK_OF[i]) * dsign(MASK_OF[j]) * rsign(ci,cj) * dsign(mk);
    ++n;
  }
  return t;
}
constexpr GPT GPt = make_gp();
constexpr JNT JNt = make_jn();
} // namespace ga

// ============================ helpers ============================
__device__ __forceinline__ float gelu_t(float x){
  const float u = 0.7978845608028654f * x * (1.0f + 0.044715f * x * x);
  return 0.5f * x * (1.0f + tanhf(u));
}
__device__ __forceinline__ void st16(float* __restrict__ p, const float* __restrict__ x){
  *(float4*)(p)    = make_float4(x[0],x[1],x[2],x[3]);
  *(float4*)(p+4)  = make_float4(x[4],x[5],x[6],x[7]);
  *(float4*)(p+8)  = make_float4(x[8],x[9],x[10],x[11]);
  *(float4*)(p+12) = make_float4(x[12],x[13],x[14],x[15]);
}
__device__ __forceinline__ int swz(int p, int byteoff){ return byteoff ^ ((p & 7) << 4); }

// ======================= prep: bcdm bf16 fragment weights =======================
__global__ void prep_bf(
    const float* __restrict__ gbo_w_mv, const float* __restrict__ gbo_w_s2mv,
    const float* __restrict__ gbo_w_mvs2s, const float* __restrict__ gbo_w_s2s,
    const float* __restrict__ l1_w_mv, const float* __restrict__ l1_w_s2mv,
    const float* __restrict__ l1_w_mvs2s, const float* __restrict__ l1_w_s2s,
    const float* __restrict__ l2_w_mv, const float* __restrict__ l2_w_s2mv,
    const float* __restrict__ l2_w_mvs2s, const float* __restrict__ l2_w_s2s,
    unsigned short* __restrict__ WBu)
{
  const int idx = blockIdx.x * 256 + threadIdx.x;
  if (idx >= TOT_BF) return;
  float v = 0.0f;
  if (idx < FB_S2MV_B) {
    const int st = idx / 36864, r2 = idx % 36864;
    const int k9 = r2 >> 12, r3 = r2 & 4095;
    const int nt = r3 >> 10, ks = (r3 >> 9) & 1, l = (r3 >> 3) & 63, e = r3 & 7;
    const int o = 16*nt + (l & 15), c = 32*ks + 8*(l >> 4) + e;
    const float* src = st==0 ? gbo_w_mv : (st==1 ? l1_w_mv : l2_w_mv);
    v = src[(o*64 + c)*9 + k9];
  } else if (idx < FB_S2S_B) {
    const float* src; int r, KS, KK;
    if (idx < FB_S2MV_C)      { r = idx - FB_S2MV_B; KS=4; KK=128; src=gbo_w_s2mv; }
    else if (idx < FB_S2MV_D) { r = idx - FB_S2MV_C; KS=8; KK=256; src=l1_w_s2mv; }
    else                      { r = idx - FB_S2MV_D; KS=8; KK=256; src=l2_w_s2mv; }
    const int per = KS*512, nt = r / per, r3 = r % per;
    const int ks = r3 >> 9, l = (r3 >> 3) & 63, e = r3 & 7;
    const int o = 16*nt + (l & 15), k = 32*ks + 8*(l >> 4) + e;
    v = src[o*KK + k];
  } else if (idx < FB_MS2S_B) {
    const float* src; int r, KS, KK;
    if (idx < FB_S2S_C)      { r = idx - FB_S2S_B; KS=4; KK=128; src=gbo_w_s2s; }
    else if (idx < FB_S2S_D) { r = idx - FB_S2S_C; KS=8; KK=256; src=l1_w_s2s; }
    else                     { r = idx - FB_S2S_D; KS=8; KK=256; src=l2_w_s2s; }
    const int per = KS*512, nt = r / per, r3 = r % per;
    const int ks = r3 >> 9, l = (r3 >> 3) & 63, e = r3 & 7;
    const int o = 16*nt + (l & 15), k = 32*ks + 8*(l >> 4) + e;
    v = src[o*KK + k];
  } else {
    const float* src; int r;
    if (idx < FB_MS2S_C)      { r = idx - FB_MS2S_B; src = gbo_w_mvs2s; }
    else if (idx < FB_MS2S_D) { r = idx - FB_MS2S_C; src = l1_w_mvs2s; }
    else                      { r = idx - FB_MS2S_D; src = l2_w_mvs2s; }
    const int nt = r >> 10, r3 = r & 1023;
    const int ks = r3 >> 9, l = (r3 >> 3) & 63, e = r3 & 7;
    const int o = 16*nt + (l & 15), k = 32*ks + 8*(l >> 4) + e;
    v = src[o*64 + k];
  }
  __bf16* WB = (__bf16*)WBu;
  const __bf16 h = (__bf16)v;
  WB[idx] = h;
  WB[TOT_BF + idx] = (__bf16)(v - (float)h);
}

// ======================= prep: stage-A bf16 fragments (hi+lo) =======================
__global__ void prep_ga(const float* __restrict__ gb_w_mv,
                        const float* __restrict__ gb_w_s2mv,
                        unsigned short* __restrict__ WBu)
{
  const int idx = blockIdx.x * 256 + threadIdx.x;
  if (idx >= SA_TOT) return;
  float v;
  if (idx < GAS2_OFF) {                 // [9k][8nt][2ks][64l][8e]
    const int k9 = idx >> 13, r3 = idx & 8191;
    const int nt = r3 >> 10, ks = (r3 >> 9) & 1, l = (r3 >> 3) & 63, e = r3 & 7;
    const int o = 16*nt + (l & 15), c = 32*ks + 8*(l >> 4) + e;
    v = gb_w_mv[(o*64 + c)*9 + k9];
  } else {                              // [8nt][4ks][64l][8e]
    const int r = idx - GAS2_OFF;
    const int nt = r >> 11, ks = (r >> 9) & 3, l = (r >> 3) & 63, e = r & 7;
    const int o = 16*nt + (l & 15), k = 32*ks + 8*(l >> 4) + e;
    v = gb_w_s2mv[o*128 + k];
  }
  __bf16* WB = (__bf16*)WBu;
  const __bf16 h = (__bf16)v;
  WB[SAW + idx] = h;
  WB[SAW + SA_TOT + idx] = (__bf16)(v - (float)h);
}

// ======================= stage_am: MFMA gb linears + GP/JOIN =======================
// 16 pts/block, 512 thr, wave nt = output rows [16nt,16nt+16) of the 128-row
// gb result (0-31 left, 32-63 right, 64-95 lj, 96-127 rj). Weights hi+lo,
// activations bf16. Output -> LDS HT bf16 (overlays XA) -> GP/JOIN fp32 -> hid.
// R14 bug: staging loop was q<2 (only 4 of 16 points staged -> NaN). Fixed: q<8.
__global__ __launch_bounds__(512, 1) void stage_am(
    const float* __restrict__ xin, const float* __restrict__ sinp,
    const float* __restrict__ gb_b_mv, const unsigned short* __restrict__ WBu,
    float* __restrict__ hid)
{
  __shared__ __align__(16) unsigned char lds[65536];   // phase1: XA 32K + SA 4K; phase2: HT 64K
  const __bf16* WB = (const __bf16*)WBu;
  const int tid = threadIdx.x, lane = tid & 63, nt = tid >> 6;
  const int pg = lane >> 4, ol = lane & 15;
  const int n0 = blockIdx.x * 16;
  constexpr int SAI = 32768;

  { // stage xin -> XA bf16 [16j][16p][64c] swizzled; sinp -> SAI
    const float4* src = (const float4*)(xin + (size_t)n0 * 1024);
    #pragma unroll
    for (int q = 0; q < 8; ++q) {          // 8*512 = 4096 float4 = full 16-pt tile
      const int i = q * 512 + tid;
      const float4 v = src[i];
      const int p = i >> 8, c = (i >> 2) & 63, j0 = (i & 3) << 2;
      const float vv[4] = {v.x, v.y, v.z, v.w};
      #pragma unroll
      for (int t = 0; t < 4; ++t)
        *(__bf16*)(lds + XA_OFF + ((((j0 + t) << 4) + p) << 7) + swz(p, 2 * c)) = (__bf16)vv[t];
    }
    {
      const float4 v = ((const float4*)(sinp + (size_t)n0 * 128))[tid];
      const int p = tid >> 5, k0 = (tid & 31) << 2;
      const float vv[4] = {v.x, v.y, v.z, v.w};
      #pragma unroll
      for (int t = 0; t < 4; ++t)
        *(__bf16*)(lds + SAI + (p << 8) + swz(p, 2 * (k0 + t))) = (__bf16)vv[t];
    }
  }
  __syncthreads();

  // ---- GEMM: acc[j] for rows o = 16nt+ol, points p = pg*4+r ----
  f32x4 acc[16];
  #pragma unroll
  for (int j = 0; j < 16; ++j) acc[j] = f32x4{0.f,0.f,0.f,0.f};
  {
    constexpr int GR[16] = {0,1,1,1,1,2,2,2,2,2,2,3,3,3,3,4};
    constexpr int PJ[16] = {-1,0,-1,-1,-1,2,3,4,-1,-1,-1,8,9,10,-1,14};
    constexpr int KE[16] = {0,5,0,0,0,6,6,6,0,0,0,7,7,7,0,8};
    const int pa  = lane & 15;
    const int cb0 = (lane >> 4) << 4;
    const int wl8 = lane << 3;
    #pragma unroll
    for (int j = 0; j < 16; ++j) {
      #pragma unroll
      for (int ks = 0; ks < 2; ++ks) {
        bf16x8 a = *(const bf16x8*)(lds + XA_OFF + (((j<<4)+pa)<<7) + swz(pa, cb0 + (ks<<6)));
        const __bf16* bp = WB + SAW + GR[j]*8192 + (nt<<10) + (ks<<9) + wl8;
        acc[j] = __builtin_amdgcn_mfma_f32_16x16x32_bf16(a, *(const bf16x8*)bp, acc[j], 0, 0, 0);
        acc[j] = __builtin_amdgcn_mfma_f32_16x16x32_bf16(a, *(const bf16x8*)(bp + SA_TOT), acc[j], 0, 0, 0);
      }
      if (PJ[j] >= 0) {
        #pragma unroll
        for (int ks = 0; ks < 2; ++ks) {
          bf16x8 a = *(const bf16x8*)(lds + XA_OFF + (((PJ[j]<<4)+pa)<<7) + swz(pa, cb0 + (ks<<6)));
          const __bf16* bp = WB + SAW + KE[j]*8192 + (nt<<10) + (ks<<9) + wl8;
          acc[j] = __builtin_amdgcn_mfma_f32_16x16x32_bf16(a, *(const bf16x8*)bp, acc[j], 0, 0, 0);
          acc[j] = __builtin_amdgcn_mfma_f32_16x16x32_bf16(a, *(const bf16x8*)(bp + SA_TOT), acc[j], 0, 0, 0);
        }
      }
    }
    // s2mv (K=128) into comp0
    #pragma unroll
    for (int ks = 0; ks < 4; ++ks) {
      bf16x8 a = *(const bf16x8*)(lds + SAI + (pa << 8) + swz(pa, cb0 + (ks << 6)));
      const __bf16* bp = WB + SAW + GAS2_OFF + (nt<<11) + (ks<<9) + wl8;
      acc[0] = __builtin_amdgcn_mfma_f32_16x16x32_bf16(a, *(const bf16x8*)bp, acc[0], 0, 0, 0);
      acc[0] = __builtin_amdgcn_mfma_f32_16x16x32_bf16(a, *(const bf16x8*)(bp + SA_TOT), acc[0], 0, 0, 0);
    }
    const float bm = gb_b_mv[16*nt + ol];
    #pragma unroll
    for (int r = 0; r < 4; ++r) acc[0][r] += bm;
  }
  __syncthreads();                     // XA/SA reads complete -> safe to overlay HT

  { // write HT bf16 [16p][128 rows][16j], row = 32B at p*4096 + (o*32 ^ ((o&12)<<3))
    const int o = 16*nt + ol;
    const int obase = (o * 32) ^ ((o & 12) << 3);
    #pragma unroll
    for (int r = 0; r < 4; ++r) {
      const int p = pg*4 + r;
      bf16x8 h0, h1;
      #pragma unroll
      for (int j = 0; j < 8; ++j) { h0[j] = (__bf16)acc[j][r]; h1[j] = (__bf16)acc[8+j][r]; }
      *(bf16x8*)(lds + (p << 12) + obase)      = h0;
      *(bf16x8*)(lds + (p << 12) + obase + 16) = h1;
    }
  }
  __syncthreads();

  { // GP + JOIN: thread = (p = tid>>5, ch = tid&31)
    const int p = tid >> 5, ch = tid & 31;
    float L[16], R[16], o16[16];
    auto ldrow = [&](int row, float* X){
      const unsigned char* q = lds + (p << 12) + ((row * 32) ^ ((row & 12) << 3));
      bf16x8 a = *(const bf16x8*)q, b = *(const bf16x8*)(q + 16);
      #pragma unroll
      for (int t = 0; t < 8; ++t) { X[t] = (float)a[t]; X[8+t] = (float)b[t]; }
    };
    ldrow(ch, L); ldrow(32 + ch, R);
    #pragma unroll
    for (int j = 0; j < 16; ++j) o16[j] = 0.0f;
    #pragma unroll
    for (int n = 0; n < 192; ++n)
      o16[ga::GPt.e[n].k] = fmaf(ga::GPt.e[n].s * L[ga::GPt.e[n].i], R[ga::GPt.e[n].j], o16[ga::GPt.e[n].k]);
    st16(hid + (((size_t)(n0 + p) * 64) + ch) * 16, o16);
    ldrow(64 + ch, L); ldrow(96 + ch, R);
    #pragma unroll
    for (int j = 0; j < 16; ++j) o16[j] = 0.0f;
    #pragma unroll
    for (int n = 0; n < 81; ++n)
      o16[ga::JNt.e[n].k] = fmaf(ga::JNt.e[n].s * L[ga::JNt.e[n].i], R[ga::JNt.e[n].j], o16[ga::JNt.e[n].k]);
    st16(hid + (((size_t)(n0 + p) * 64) + 32 + ch) * 16, o16);
  }
}

// ======================= bcdm helpers (hi-only MFMA) =======================
template<int JH>
__device__ __forceinline__ void mv_half(f32x4 (&acc)[8], const __bf16* __restrict__ WB,
                                        const unsigned char* lds, int mvbase, int w, int lane)
{
  constexpr int GRa[2][8] = {{0,1,1,1,1,2,2,2},{2,2,2,3,3,3,3,4}};
  constexpr int PJa[2][8] = {{-1,0,-1,-1,-1,2,3,4},{-1,-1,-1,8,9,10,-1,14}};
  constexpr int KEa[2][8] = {{0,5,0,0,0,6,6,6},{0,0,0,7,7,7,0,8}};
  const int pa  = lane & 15;
  const int cb0 = (lane >> 4) << 4;
  const int wl8 = lane << 3;
  #pragma unroll
  for (int jl = 0; jl < 8; ++jl) {
    const int j = JH*8 + jl;
    #pragma unroll
    for (int ks = 0; ks < 2; ++ks) {
      bf16x8 a = *(const bf16x8*)(lds + XA_OFF + (((j<<4)+pa)<<7) + swz(pa, cb0 + (ks<<6)));
      const __bf16* bp = WB + mvbase + GRa[JH][jl]*4096 + (w<<10) + (ks<<9) + wl8;
      acc[jl] = __builtin_amdgcn_mfma_f32_16x16x32_bf16(a, *(const bf16x8*)bp, acc[jl], 0, 0, 0);
    }
    if (PJa[JH][jl] >= 0) {
      #pragma unroll
      for (int ks = 0; ks < 2; ++ks) {
        bf16x8 a = *(const bf16x8*)(lds + XA_OFF + (((PJa[JH][jl]<<4)+pa)<<7) + swz(pa, cb0 + (ks<<6)));
        const __bf16* bp = WB + mvbase + KEa[JH][jl]*4096 + (w<<10) + (ks<<9) + wl8;
        acc[jl] = __builtin_amdgcn_mfma_f32_16x16x32_bf16(a, *(const bf16x8*)bp, acc[jl], 0, 0, 0);
      }
    }
  }
}
template<int KS, int RSH>
__device__ __forceinline__ void s_gemm(f32x4& acc, const __bf16* __restrict__ WB,
                                       const unsigned char* lds, int abase, int wbase, int lane)
{
  const int pa  = lane & 15;
  const int cb0 = (lane >> 4) << 4;
  const int wl8 = lane << 3;
  #pragma unroll
  for (int ks = 0; ks < KS; ++ks) {
    bf16x8 a = *(const bf16x8*)(lds + abase + (pa << RSH) + swz(pa, cb0 + (ks << 6)));
    const __bf16* bp = WB + wbase + (ks << 9) + wl8;
    acc = __builtin_amdgcn_mfma_f32_16x16x32_bf16(a, *(const bf16x8*)bp, acc, 0, 0, 0);
  }
}

// ======================= bcdm (unchanged from R13) =======================
__global__ __launch_bounds__(512, 1) void bcdm(
    const float* __restrict__ sinp,
    const float* __restrict__ gbo_b_mv, const float* __restrict__ gbo_b_s,
    const float* __restrict__ l1_b_mv,  const float* __restrict__ l1_b_s,
    const float* __restrict__ l2_b_mv,  const float* __restrict__ l2_b_s,
    const unsigned short* __restrict__ WBu,
    float* __restrict__ out)
{
  __shared__ __align__(16) unsigned char lds[LDS_BYTES];
  const __bf16* WB = (const __bf16*)WBu;
  const int tid = threadIdx.x, lane = tid & 63, wv = tid >> 6;
  const int w = wv & 3, jh = wv >> 2;
  const int pg = lane >> 4, ol = lane & 15;
  const int n0 = blockIdx.x * 16;

  { // stage hidden -> XA bf16, + C0, + SA
    const float4* hsrc = (const float4*)(out + (size_t)n0 * 1024);
    #pragma unroll
    for (int q = 0; q < 8; ++q) {
      const int i = q * 512 + tid;
      const float4 v = hsrc[i];
      const int p = i >> 8, c = (i >> 2) & 63, j0 = (i & 3) << 2;
      const float vv[4] = {v.x, v.y, v.z, v.w};
      #pragma unroll
      for (int t = 0; t < 4; ++t)
        *(__bf16*)(lds + XA_OFF + ((((j0 + t) << 4) + p) << 7) + swz(p, 2 * c)) = (__bf16)vv[t];
      if (j0 == 0)
        *(__bf16*)(lds + C0_OFF + (p << 7) + swz(p, 2 * c)) = (__bf16)v.x;
    }
    {
      const float4 v = ((const float4*)(sinp + (size_t)n0 * 128))[tid];
      const int p = tid >> 5, k0 = (tid & 31) << 2;
      const float vv[4] = {v.x, v.y, v.z, v.w};
      #pragma unroll
      for (int t = 0; t < 4; ++t)
        *(__bf16*)(lds + SA_OFF + (p << 8) + swz(p, 2 * (k0 + t))) = (__bf16)vv[t];
    }
  }
  __syncthreads();

  float* REDEQ = (float*)(lds + RED_OFF);        // [8][16]
  float* REDS  = REDEQ + 128;
  float* REDQ  = REDEQ + 256;
  float* GT    = (float*)(lds + GT_OFF);         // [16p][64o]

  #pragma unroll 1
  for (int stage = 0; stage < 2; ++stage) {
    const int mvb   = stage == 0 ? FB_MVB    : FB_MVC;
    const int s2mvb = stage == 0 ? FB_S2MV_B : FB_S2MV_C;
    const int s2sb  = stage == 0 ? FB_S2S_B  : FB_S2S_C;
    const int ms2sb = stage == 0 ? FB_MS2S_B : FB_MS2S_C;
    const int sab   = stage == 0 ? SA_OFF    : T1_OFF;
    const int tdst  = stage == 0 ? T1_OFF    : T2_OFF;
    const float* b_mv = stage == 0 ? gbo_b_mv : l1_b_mv;
    const float* b_s  = stage == 0 ? gbo_b_s  : l1_b_s;
    const int nt0 = 4*w + 2*jh;

    f32x4 acc[8], fac[2];
    #pragma unroll
    for (int j = 0; j < 8; ++j) acc[j] = f32x4{0.f,0.f,0.f,0.f};
    fac[0] = f32x4{0.f,0.f,0.f,0.f}; fac[1] = f32x4{0.f,0.f,0.f,0.f};

    if (jh == 0) mv_half<0>(acc, WB, lds, mvb, w, lane);
    else         mv_half<1>(acc, WB, lds, mvb, w, lane);

    if (stage == 0) {
      if (jh == 0) s_gemm<4,8>(acc[0], WB, lds, sab, s2mvb + w*2048, lane);
      #pragma unroll
      for (int i = 0; i < 2; ++i) {
        s_gemm<4,8>(fac[i], WB, lds, sab, s2sb + (nt0+i)*2048, lane);
        s_gemm<2,7>(fac[i], WB, lds, C0_OFF, ms2sb + (nt0+i)*1024, lane);
      }
    } else {
      if (jh == 0) s_gemm<8,9>(acc[0], WB, lds, sab, s2mvb + w*4096, lane);
      #pragma unroll
      for (int i = 0; i < 2; ++i) {
        s_gemm<8,9>(fac[i], WB, lds, sab, s2sb + (nt0+i)*4096, lane);
        s_gemm<2,7>(fac[i], WB, lds, C0_OFF, ms2sb + (nt0+i)*1024, lane);
      }
    }
    __syncthreads();

    if (jh == 0) {
      const float bm = b_mv[16*w + ol];
      #pragma unroll
      for (int r = 0; r < 4; ++r) acc[0][r] += bm;
    }
    #pragma unroll
    for (int i = 0; i < 2; ++i) {
      const float bs = b_s[16*(nt0+i) + ol];
      #pragma unroll
      for (int r = 0; r < 4; ++r) fac[i][r] += bs;
    }
    float sq[4], sm[4], s2[4];
    #pragma unroll
    for (int r = 0; r < 4; ++r) {
      sq[r] = (jh == 0)
        ? acc[0][r]*acc[0][r] + acc[2][r]*acc[2][r] + acc[3][r]*acc[3][r] + acc[4][r]*acc[4][r]
        : acc[0][r]*acc[0][r] + acc[1][r]*acc[1][r] + acc[2][r]*acc[2][r] + acc[6][r]*acc[6][r];
      sm[r] = fac[0][r] + fac[1][r];
      s2[r] = fac[0][r]*fac[0][r] + fac[1][r]*fac[1][r];
    }
    #pragma unroll
    for (int m = 1; m < 16; m <<= 1) {
      #pragma unroll
      for (int r = 0; r < 4; ++r) {
        sq[r] += __shfl_xor(sq[r], m);
        sm[r] += __shfl_xor(sm[r], m);
        s2[r] += __shfl_xor(s2[r], m);
      }
    }
    if (ol == 0) {
      #pragma unroll
      for (int r = 0; r < 4; ++r) {
        const int p = pg*4 + r;
        REDEQ[wv*16 + p] = sq[r]; REDS[wv*16 + p] = sm[r]; REDQ[wv*16 + p] = s2[r];
      }
    }
    __syncthreads();

    float rs[4], mu[4], rstd[4];
    #pragma unroll
    for (int r = 0; r < 4; ++r) {
      const int p = pg*4 + r;
      float te = 0.f, ts = 0.f, tq = 0.f;
      #pragma unroll
      for (int v2 = 0; v2 < 8; ++v2) { te += REDEQ[v2*16+p]; ts += REDS[v2*16+p]; tq += REDQ[v2*16+p]; }
      rs[r]   = 1.0f / sqrtf(fmaxf(te * (1.0f/64.0f), 0.01f));
      mu[r]   = ts * (1.0f/256.0f);
      rstd[r] = rsqrtf(tq * (1.0f/256.0f) - mu[r]*mu[r] + 1e-5f);
    }
    #pragma unroll
    for (int i = 0; i < 2; ++i) {
      #pragma unroll
      for (int r = 0; r < 4; ++r) {
        const int p = pg*4 + r, op = 16*(nt0+i) + ol;
        *(__bf16*)(lds + tdst + (p << 9) + swz(p, 2*op)) =
            (__bf16)gelu_t((fac[i][r] - mu[r]) * rstd[r]);
      }
    }
    if (jh == 0) {
      const int cnew = 16*w + ol;
      #pragma unroll
      for (int r = 0; r < 4; ++r) {
        const int p = pg*4 + r;
        const float a0n = acc[0][r] * rs[r];
        const float g   = gelu_t(a0n);
        GT[p*64 + cnew] = g;
        *(__bf16*)(lds + C0_OFF + (p<<7) + swz(p, 2*cnew)) = (__bf16)(g * a0n);
      }
    }
    __syncthreads();

    {
      const int cnew = 16*w + ol;
      float f[4];
      #pragma unroll
      for (int r = 0; r < 4; ++r) f[r] = rs[r] * GT[(pg*4+r)*64 + cnew];
      #pragma unroll
      for (int jl = 0; jl < 8; ++jl) {
        const int j = jh*8 + jl;
        #pragma unroll
        for (int r = 0; r < 4; ++r) {
          const int p = pg*4 + r;
          *(__bf16*)(lds + XA_OFF + (((j<<4)+p)<<7) + swz(p, 2*cnew)) = (__bf16)(acc[jl][r] * f[r]);
        }
      }
    }
    __syncthreads();
  }

  {
    f32x4 acc[8], fac2;
    #pragma unroll
    for (int j = 0; j < 8; ++j) acc[j] = f32x4{0.f,0.f,0.f,0.f};
    fac2 = f32x4{0.f,0.f,0.f,0.f};

    if (jh == 0) mv_half<0>(acc, WB, lds, FB_MVD, w, lane);
    else         mv_half<1>(acc, WB, lds, FB_MVD, w, lane);
    if (jh == 0) s_gemm<8,9>(acc[0], WB, lds, T2_OFF, FB_S2MV_D + w*4096, lane);
    const int ntd = w + 4*jh;
    s_gemm<8,9>(fac2, WB, lds, T2_OFF, FB_S2S_D + ntd*4096, lane);
    s_gemm<2,7>(fac2, WB, lds, C0_OFF, FB_MS2S_D + ntd*1024, lane);

    if (jh == 0) {
      const float bm = l2_b_mv[16*w + ol];
      #pragma unroll
      for (int r = 0; r < 4; ++r) acc[0][r] += bm;
    }
    #pragma unroll
    for (int r = 0; r < 4; ++r) {
      const int p = pg*4 + r;
      float* dst = out + ((size_t)(n0 + p)*64 + 16*w + ol)*16 + jh*8;
      *(float4*)(dst+0) = make_float4(acc[0][r], acc[1][r], acc[2][r], acc[3][r]);
      *(float4*)(dst+4) = make_float4(acc[4][r], acc[5][r], acc[6][r], acc[7][r]);
    }
    {
      const int od = 16*ntd + ol;
      const float bs = l2_b_s[od];
      #pragma unroll
      for (int r = 0; r < 4; ++r) {
        const int p = pg*4 + r;
        out[SOFF + (size_t)(n0 + p)*128 + od] = fac2[r] + bs;
      }
    }
  }
}

// ============================ host launch ============================
extern "C" void kernel_launch(void* const* d_in, const int* in_sizes, int n_in,
                              void* d_out, int out_size, void* d_ws, size_t ws_size,
                              hipStream_t stream) {
  const float* xin          = (const float*)d_in[0];
  const float* sinp         = (const float*)d_in[1];
  const float* gb_w_mv      = (const float*)d_in[2];
  const float* gb_w_s2mv    = (const float*)d_in[3];
  const float* gb_b_mv      = (const float*)d_in[4];
  const float* gbo_w_mv     = (const float*)d_in[5];
  const float* gbo_w_s2mv   = (const float*)d_in[6];
  const float* gbo_b_mv     = (const float*)d_in[7];
  const float* gbo_w_mvs2s  = (const float*)d_in[8];
  const float* gbo_w_s2s    = (const float*)d_in[9];
  const float* gbo_b_s      = (const float*)d_in[10];
  const float* l1_w_mv      = (const float*)d_in[11];
  const float* l1_w_s2mv    = (const float*)d_in[12];
  const float* l1_b_mv      = (const float*)d_in[13];
  const float* l1_w_mvs2s   = (const float*)d_in[14];
  const float* l1_w_s2s     = (const float*)d_in[15];
  const float* l1_b_s       = (const float*)d_in[16];
  const float* l2_w_mv      = (const float*)d_in[17];
  const float* l2_w_s2mv    = (const float*)d_in[18];
  const float* l2_b_mv      = (const float*)d_in[19];
  const float* l2_w_mvs2s   = (const float*)d_in[20];
  const float* l2_w_s2s     = (const float*)d_in[21];
  const float* l2_b_s       = (const float*)d_in[22];
  unsigned short* WBu = (unsigned short*)d_ws;
  float* out = (float*)d_out;

  prep_bf<<<(TOT_BF + 255) / 256, 256, 0, stream>>>(
      gbo_w_mv, gbo_w_s2mv, gbo_w_mvs2s, gbo_w_s2s,
      l1_w_mv, l1_w_s2mv, l1_w_mvs2s, l1_w_s2s,
      l2_w_mv, l2_w_s2mv, l2_w_mvs2s, l2_w_s2s, WBu);

  prep_ga<<<(SA_TOT + 255) / 256, 256, 0, stream>>>(gb_w_mv, gb_w_s2mv, WBu);

  stage_am<<<NPTS / 16, 512, 0, stream>>>(xin, sinp, gb_b_mv, WBu, out);

  bcdm<<<NPTS / 16, 512, 0, stream>>>(
      sinp, gbo_b_mv, gbo_b_s, l1_b_mv, l1_b_s, l2_b_mv, l2_b_s, WBu, out);
}

// Round 16
// 395.818 us; speedup vs baseline: 2.5426x; 1.1796x over previous
//
#include <hip/hip_runtime.h>
#include <math.h>

typedef __bf16 bf16x8 __attribute__((ext_vector_type(8)));
typedef float  f32x4  __attribute__((ext_vector_type(4)));

// ============================ constants ============================
constexpr int NPTS = 32768;
constexpr long long SOFF = 33554432LL;        // NPTS*64*16, start of scalar outputs

// ---- bf16 fragment region (all weights), element offsets in WBu ----
constexpr int TOT_BF   = 323584;
constexpr int FB_MVB    = 0;
constexpr int FB_MVC    = 36864;
constexpr int FB_MVD    = 73728;
constexpr int FB_S2MV_B = 110592;
constexpr int FB_S2MV_C = 118784;
constexpr int FB_S2MV_D = 135168;
constexpr int FB_S2S_B  = 151552;
constexpr int FB_S2S_C  = 184320;
constexpr int FB_S2S_D  = 249856;
constexpr int FB_MS2S_B = 282624;
constexpr int FB_MS2S_C = 299008;
constexpr int FB_MS2S_D = 315392;
// stage-A frags: hi at [SAW, SAW+SA_TOT), lo at [SAW+SA_TOT, SAW+2*SA_TOT)
constexpr int SAW      = 647168;
constexpr int GAS2_OFF = 73728;
constexpr int SA_TOT   = 90112;

// ---- fused LDS layout (bytes) ----
// [0,65536): phase-A XA(32K) -> HT(64K) -> {XA(new)+T1+T2+C0+GT+RED}
// [65536,69632): SA (staged sinp, persists across A and B phases)
constexpr int XA_OFF  = 0;        // bf16 [16j][16p][64c] swizzled, 32768
constexpr int T1_OFF  = 36864;    // bf16 [16p][256] swizzled, 8192
constexpr int T2_OFF  = 45056;    // 8192
constexpr int C0_OFF  = 53248;    // bf16 [16p][64] swizzled, 2048
constexpr int GT_OFF  = 55296;    // f32 [16p][64o] gate, 4096
constexpr int RED_OFF = 59392;    // 3 x f32[8wv][16p] = 1536 (ends 60928)
constexpr int SA_OFF  = 65536;    // bf16 [16p][128] swizzled, 4096
constexpr int LDS_BYTES = 69632;  // 2 blocks/CU (139264 <= 163840)

// ==================== compile-time GA tables (GP/JOIN) ====================
namespace ga {
constexpr int MASK_OF[16] = {0,1,2,4,8,3,5,9,6,10,12,7,11,13,14,15};
constexpr int idx_of_mask(int m){ int r = 0; for(int i=0;i<16;++i) if(MASK_OF[i]==m) r=i; return r; }
constexpr int pcount(int x){ int c=0; while(x){ c += x&1; x >>= 1; } return c; }
constexpr int nswaps(int a,int b){ int s=0; a >>= 1; while(a){ s += pcount(a&b); a >>= 1; } return s; }
constexpr float rsign(int a,int b){ return (nswaps(a,b)&1) ? -1.0f : 1.0f; }
constexpr float dsign(int m){ return rsign(m, 15^m); }
struct Ent { int i, j, k; float s; };
struct GPT { Ent e[192]; };
constexpr GPT make_gp(){
  GPT t{}; int n=0;
  for(int i=0;i<16;++i) for(int j=0;j<16;++j){
    const int a=MASK_OF[i], b=MASK_OF[j];
    if((a & b & 1) != 0) continue;
    t.e[n].i=i; t.e[n].j=j; t.e[n].k=idx_of_mask(a^b); t.e[n].s=rsign(a,b); ++n;
  }
  return t;
}
struct JNT { Ent e[81]; };
constexpr JNT make_jn(){
  JNT t{}; int n=0;
  for(int i=0;i<16;++i) for(int j=0;j<16;++j){
    const int ci = 15 ^ MASK_OF[i], cj = 15 ^ MASK_OF[j];
    if((ci & cj) != 0) continue;
    const int mr = ci ^ cj, mk = 15 ^ mr;
    t.e[n].i=i; t.e[n].j=j; t.e[n].k=idx_of_mask(mk);
    t.e[n].s = dsign(MASK_OF[i]) * dsign(MASK_OF[j]) * rsign(ci,cj) * dsign(mk);
    ++n;
  }
  return t;
}
constexpr GPT GPt = make_gp();
constexpr JNT JNt = make_jn();
} // namespace ga

// ============================ helpers ============================
__device__ __forceinline__ float gelu_t(float x){
  const float u = 0.7978845608028654f * x * (1.0f + 0.044715f * x * x);
  return 0.5f * x * (1.0f + tanhf(u));
}
__device__ __forceinline__ int swz(int p, int byteoff){ return byteoff ^ ((p & 7) << 4); }

// ======================= prep: bcdm bf16 fragment weights =======================
__global__ void prep_bf(
    const float* __restrict__ gbo_w_mv, const float* __restrict__ gbo_w_s2mv,
    const float* __restrict__ gbo_w_mvs2s, const float* __restrict__ gbo_w_s2s,
    const float* __restrict__ l1_w_mv, const float* __restrict__ l1_w_s2mv,
    const float* __restrict__ l1_w_mvs2s, const float* __restrict__ l1_w_s2s,
    const float* __restrict__ l2_w_mv, const float* __restrict__ l2_w_s2mv,
    const float* __restrict__ l2_w_mvs2s, const float* __restrict__ l2_w_s2s,
    unsigned short* __restrict__ WBu)
{
  const int idx = blockIdx.x * 256 + threadIdx.x;
  if (idx >= TOT_BF) return;
  float v = 0.0f;
  if (idx < FB_S2MV_B) {
    const int st = idx / 36864, r2 = idx % 36864;
    const int k9 = r2 >> 12, r3 = r2 & 4095;
    const int nt = r3 >> 10, ks = (r3 >> 9) & 1, l = (r3 >> 3) & 63, e = r3 & 7;
    const int o = 16*nt + (l & 15), c = 32*ks + 8*(l >> 4) + e;
    const float* src = st==0 ? gbo_w_mv : (st==1 ? l1_w_mv : l2_w_mv);
    v = src[(o*64 + c)*9 + k9];
  } else if (idx < FB_S2S_B) {
    const float* src; int r, KS, KK;
    if (idx < FB_S2MV_C)      { r = idx - FB_S2MV_B; KS=4; KK=128; src=gbo_w_s2mv; }
    else if (idx < FB_S2MV_D) { r = idx - FB_S2MV_C; KS=8; KK=256; src=l1_w_s2mv; }
    else                      { r = idx - FB_S2MV_D; KS=8; KK=256; src=l2_w_s2mv; }
    const int per = KS*512, nt = r / per, r3 = r % per;
    const int ks = r3 >> 9, l = (r3 >> 3) & 63, e = r3 & 7;
    const int o = 16*nt + (l & 15), k = 32*ks + 8*(l >> 4) + e;
    v = src[o*KK + k];
  } else if (idx < FB_MS2S_B) {
    const float* src; int r, KS, KK;
    if (idx < FB_S2S_C)      { r = idx - FB_S2S_B; KS=4; KK=128; src=gbo_w_s2s; }
    else if (idx < FB_S2S_D) { r = idx - FB_S2S_C; KS=8; KK=256; src=l1_w_s2s; }
    else                     { r = idx - FB_S2S_D; KS=8; KK=256; src=l2_w_s2s; }
    const int per = KS*512, nt = r / per, r3 = r % per;
    const int ks = r3 >> 9, l = (r3 >> 3) & 63, e = r3 & 7;
    const int o = 16*nt + (l & 15), k = 32*ks + 8*(l >> 4) + e;
    v = src[o*KK + k];
  } else {
    const float* src; int r;
    if (idx < FB_MS2S_C)      { r = idx - FB_MS2S_B; src = gbo_w_mvs2s; }
    else if (idx < FB_MS2S_D) { r = idx - FB_MS2S_C; src = l1_w_mvs2s; }
    else                      { r = idx - FB_MS2S_D; src = l2_w_mvs2s; }
    const int nt = r >> 10, r3 = r & 1023;
    const int ks = r3 >> 9, l = (r3 >> 3) & 63, e = r3 & 7;
    const int o = 16*nt + (l & 15), k = 32*ks + 8*(l >> 4) + e;
    v = src[o*64 + k];
  }
  __bf16* WB = (__bf16*)WBu;
  const __bf16 h = (__bf16)v;
  WB[idx] = h;
  WB[TOT_BF + idx] = (__bf16)(v - (float)h);
}

// ======================= prep: stage-A bf16 fragments (hi+lo) =======================
__global__ void prep_ga(const float* __restrict__ gb_w_mv,
                        const float* __restrict__ gb_w_s2mv,
                        unsigned short* __restrict__ WBu)
{
  const int idx = blockIdx.x * 256 + threadIdx.x;
  if (idx >= SA_TOT) return;
  float v;
  if (idx < GAS2_OFF) {                 // [9k][8nt][2ks][64l][8e]
    const int k9 = idx >> 13, r3 = idx & 8191;
    const int nt = r3 >> 10, ks = (r3 >> 9) & 1, l = (r3 >> 3) & 63, e = r3 & 7;
    const int o = 16*nt + (l & 15), c = 32*ks + 8*(l >> 4) + e;
    v = gb_w_mv[(o*64 + c)*9 + k9];
  } else {                              // [8nt][4ks][64l][8e]
    const int r = idx - GAS2_OFF;
    const int nt = r >> 11, ks = (r >> 9) & 3, l = (r >> 3) & 63, e = r & 7;
    const int o = 16*nt + (l & 15), k = 32*ks + 8*(l >> 4) + e;
    v = gb_w_s2mv[o*128 + k];
  }
  __bf16* WB = (__bf16*)WBu;
  const __bf16 h = (__bf16)v;
  WB[SAW + idx] = h;
  WB[SAW + SA_TOT + idx] = (__bf16)(v - (float)h);
}

// ======================= MFMA helpers =======================
template<int JH>
__device__ __forceinline__ void mv_half(f32x4 (&acc)[8], const __bf16* __restrict__ WB,
                                        const unsigned char* lds, int mvbase, int w, int lane)
{
  constexpr int GRa[2][8] = {{0,1,1,1,1,2,2,2},{2,2,2,3,3,3,3,4}};
  constexpr int PJa[2][8] = {{-1,0,-1,-1,-1,2,3,4},{-1,-1,-1,8,9,10,-1,14}};
  constexpr int KEa[2][8] = {{0,5,0,0,0,6,6,6},{0,0,0,7,7,7,0,8}};
  const int pa  = lane & 15;
  const int cb0 = (lane >> 4) << 4;
  const int wl8 = lane << 3;
  #pragma unroll
  for (int jl = 0; jl < 8; ++jl) {
    const int j = JH*8 + jl;
    #pragma unroll
    for (int ks = 0; ks < 2; ++ks) {
      bf16x8 a = *(const bf16x8*)(lds + XA_OFF + (((j<<4)+pa)<<7) + swz(pa, cb0 + (ks<<6)));
      const __bf16* bp = WB + mvbase + GRa[JH][jl]*4096 + (w<<10) + (ks<<9) + wl8;
      acc[jl] = __builtin_amdgcn_mfma_f32_16x16x32_bf16(a, *(const bf16x8*)bp, acc[jl], 0, 0, 0);
    }
    if (PJa[JH][jl] >= 0) {
      #pragma unroll
      for (int ks = 0; ks < 2; ++ks) {
        bf16x8 a = *(const bf16x8*)(lds + XA_OFF + (((PJa[JH][jl]<<4)+pa)<<7) + swz(pa, cb0 + (ks<<6)));
        const __bf16* bp = WB + mvbase + KEa[JH][jl]*4096 + (w<<10) + (ks<<9) + wl8;
        acc[jl] = __builtin_amdgcn_mfma_f32_16x16x32_bf16(a, *(const bf16x8*)bp, acc[jl], 0, 0, 0);
      }
    }
  }
}
template<int KS, int RSH>
__device__ __forceinline__ void s_gemm(f32x4& acc, const __bf16* __restrict__ WB,
                                       const unsigned char* lds, int abase, int wbase, int lane)
{
  const int pa  = lane & 15;
  const int cb0 = (lane >> 4) << 4;
  const int wl8 = lane << 3;
  #pragma unroll
  for (int ks = 0; ks < KS; ++ks) {
    bf16x8 a = *(const bf16x8*)(lds + abase + (pa << RSH) + swz(pa, cb0 + (ks << 6)));
    const __bf16* bp = WB + wbase + (ks << 9) + wl8;
    acc = __builtin_amdgcn_mfma_f32_16x16x32_bf16(a, *(const bf16x8*)bp, acc, 0, 0, 0);
  }
}

// ======================= fused_all: A + GP/JOIN + B/C/D =======================
// 16 pts/block, 512 thr. hid never touches HBM: A-GEMM -> HT(LDS) -> GP/JOIN
// (regs) -> XA(LDS) -> bcdm stages. SA (sinp) staged once, shared by A and B.
__global__ __launch_bounds__(512, 1) void fused_all(
    const float* __restrict__ xin,  const float* __restrict__ sinp,
    const float* __restrict__ gb_b_mv,
    const float* __restrict__ gbo_b_mv, const float* __restrict__ gbo_b_s,
    const float* __restrict__ l1_b_mv,  const float* __restrict__ l1_b_s,
    const float* __restrict__ l2_b_mv,  const float* __restrict__ l2_b_s,
    const unsigned short* __restrict__ WBu,
    float* __restrict__ out)
{
  __shared__ __align__(16) unsigned char lds[LDS_BYTES];
  const __bf16* WB = (const __bf16*)WBu;
  const int tid = threadIdx.x, lane = tid & 63, wv = tid >> 6;
  const int pg = lane >> 4, ol = lane & 15;
  const int n0 = blockIdx.x * 16;

  // ---------------- phase A: stage xin -> XA, sinp -> SA ----------------
  {
    const float4* src = (const float4*)(xin + (size_t)n0 * 1024);
    #pragma unroll
    for (int q = 0; q < 8; ++q) {
      const int i = q * 512 + tid;
      const float4 v = src[i];
      const int p = i >> 8, c = (i >> 2) & 63, j0 = (i & 3) << 2;
      const float vv[4] = {v.x, v.y, v.z, v.w};
      #pragma unroll
      for (int t = 0; t < 4; ++t)
        *(__bf16*)(lds + XA_OFF + ((((j0 + t) << 4) + p) << 7) + swz(p, 2 * c)) = (__bf16)vv[t];
    }
    {
      const float4 v = ((const float4*)(sinp + (size_t)n0 * 128))[tid];
      const int p = tid >> 5, k0 = (tid & 31) << 2;
      const float vv[4] = {v.x, v.y, v.z, v.w};
      #pragma unroll
      for (int t = 0; t < 4; ++t)
        *(__bf16*)(lds + SA_OFF + (p << 8) + swz(p, 2 * (k0 + t))) = (__bf16)vv[t];
    }
  }
  __syncthreads();

  // ---------------- phase A GEMM (hi+lo), wave nt = rows [16nt,16nt+16) ----------------
  {
    const int nt = wv;
    f32x4 acc[16];
    #pragma unroll
    for (int j = 0; j < 16; ++j) acc[j] = f32x4{0.f,0.f,0.f,0.f};
    {
      constexpr int GR[16] = {0,1,1,1,1,2,2,2,2,2,2,3,3,3,3,4};
      constexpr int PJ[16] = {-1,0,-1,-1,-1,2,3,4,-1,-1,-1,8,9,10,-1,14};
      constexpr int KE[16] = {0,5,0,0,0,6,6,6,0,0,0,7,7,7,0,8};
      const int pa  = lane & 15;
      const int cb0 = (lane >> 4) << 4;
      const int wl8 = lane << 3;
      #pragma unroll
      for (int j = 0; j < 16; ++j) {
        #pragma unroll
        for (int ks = 0; ks < 2; ++ks) {
          bf16x8 a = *(const bf16x8*)(lds + XA_OFF + (((j<<4)+pa)<<7) + swz(pa, cb0 + (ks<<6)));
          const __bf16* bp = WB + SAW + GR[j]*8192 + (nt<<10) + (ks<<9) + wl8;
          acc[j] = __builtin_amdgcn_mfma_f32_16x16x32_bf16(a, *(const bf16x8*)bp, acc[j], 0, 0, 0);
          acc[j] = __builtin_amdgcn_mfma_f32_16x16x32_bf16(a, *(const bf16x8*)(bp + SA_TOT), acc[j], 0, 0, 0);
        }
        if (PJ[j] >= 0) {
          #pragma unroll
          for (int ks = 0; ks < 2; ++ks) {
            bf16x8 a = *(const bf16x8*)(lds + XA_OFF + (((PJ[j]<<4)+pa)<<7) + swz(pa, cb0 + (ks<<6)));
            const __bf16* bp = WB + SAW + KE[j]*8192 + (nt<<10) + (ks<<9) + wl8;
            acc[j] = __builtin_amdgcn_mfma_f32_16x16x32_bf16(a, *(const bf16x8*)bp, acc[j], 0, 0, 0);
            acc[j] = __builtin_amdgcn_mfma_f32_16x16x32_bf16(a, *(const bf16x8*)(bp + SA_TOT), acc[j], 0, 0, 0);
          }
        }
      }
      #pragma unroll
      for (int ks = 0; ks < 4; ++ks) {
        bf16x8 a = *(const bf16x8*)(lds + SA_OFF + (pa << 8) + swz(pa, cb0 + (ks << 6)));
        const __bf16* bp = WB + SAW + GAS2_OFF + (nt<<11) + (ks<<9) + wl8;
        acc[0] = __builtin_amdgcn_mfma_f32_16x16x32_bf16(a, *(const bf16x8*)bp, acc[0], 0, 0, 0);
        acc[0] = __builtin_amdgcn_mfma_f32_16x16x32_bf16(a, *(const bf16x8*)(bp + SA_TOT), acc[0], 0, 0, 0);
      }
      const float bm = gb_b_mv[16*nt + ol];
      #pragma unroll
      for (int r = 0; r < 4; ++r) acc[0][r] += bm;
    }
    __syncthreads();                   // XA reads complete -> overlay HT

    { // write HT bf16 [16p][128 rows][16j], row at p*4096 + (o*32 ^ ((o&12)<<3))
      const int o = 16*nt + ol;
      const int obase = (o * 32) ^ ((o & 12) << 3);
      #pragma unroll
      for (int r = 0; r < 4; ++r) {
        const int p = pg*4 + r;
        bf16x8 h0, h1;
        #pragma unroll
        for (int j = 0; j < 8; ++j) { h0[j] = (__bf16)acc[j][r]; h1[j] = (__bf16)acc[8+j][r]; }
        *(bf16x8*)(lds + (p << 12) + obase)      = h0;
        *(bf16x8*)(lds + (p << 12) + obase + 16) = h1;
      }
    }
  }
  __syncthreads();

  // ---------------- GP + JOIN into registers ----------------
  float gpo[16], jno[16];
  {
    const int p2 = tid >> 5, ch = tid & 31;
    float L[16], R[16];
    auto ldrow = [&](int row, float* X){
      const unsigned char* q = lds + (p2 << 12) + ((row * 32) ^ ((row & 12) << 3));
      bf16x8 a = *(const bf16x8*)q, b = *(const bf16x8*)(q + 16);
      #pragma unroll
      for (int t = 0; t < 8; ++t) { X[t] = (float)a[t]; X[8+t] = (float)b[t]; }
    };
    ldrow(ch, L); ldrow(32 + ch, R);
    #pragma unroll
    for (int j = 0; j < 16; ++j) gpo[j] = 0.0f;
    #pragma unroll
    for (int n = 0; n < 192; ++n)
      gpo[ga::GPt.e[n].k] = fmaf(ga::GPt.e[n].s * L[ga::GPt.e[n].i], R[ga::GPt.e[n].j], gpo[ga::GPt.e[n].k]);
    ldrow(64 + ch, L); ldrow(96 + ch, R);
    #pragma unroll
    for (int j = 0; j < 16; ++j) jno[j] = 0.0f;
    #pragma unroll
    for (int n = 0; n < 81; ++n)
      jno[ga::JNt.e[n].k] = fmaf(ga::JNt.e[n].s * L[ga::JNt.e[n].i], R[ga::JNt.e[n].j], jno[ga::JNt.e[n].k]);
  }
  __syncthreads();                     // HT reads complete -> overlay XA/C0

  { // write hidden -> XA bf16 [16j][16p][64c] + C0; thread owns (p2, ch) and (p2, 32+ch)
    const int p2 = tid >> 5, ch = tid & 31;
    #pragma unroll
    for (int j = 0; j < 16; ++j) {
      *(__bf16*)(lds + XA_OFF + (((j<<4)+p2)<<7) + swz(p2, 2*ch))      = (__bf16)gpo[j];
      *(__bf16*)(lds + XA_OFF + (((j<<4)+p2)<<7) + swz(p2, 2*(32+ch))) = (__bf16)jno[j];
    }
    *(__bf16*)(lds + C0_OFF + (p2<<7) + swz(p2, 2*ch))      = (__bf16)gpo[0];
    *(__bf16*)(lds + C0_OFF + (p2<<7) + swz(p2, 2*(32+ch))) = (__bf16)jno[0];
  }
  __syncthreads();

  // ---------------- phases B, C, D (bcdm, hi-only) ----------------
  const int w = wv & 3, jh = wv >> 2;
  float* REDEQ = (float*)(lds + RED_OFF);        // [8][16]
  float* REDS  = REDEQ + 128;
  float* REDQ  = REDEQ + 256;
  float* GT    = (float*)(lds + GT_OFF);         // [16p][64o]

  #pragma unroll 1
  for (int stage = 0; stage < 2; ++stage) {
    const int mvb   = stage == 0 ? FB_MVB    : FB_MVC;
    const int s2mvb = stage == 0 ? FB_S2MV_B : FB_S2MV_C;
    const int s2sb  = stage == 0 ? FB_S2S_B  : FB_S2S_C;
    const int ms2sb = stage == 0 ? FB_MS2S_B : FB_MS2S_C;
    const int sab   = stage == 0 ? SA_OFF    : T1_OFF;
    const int tdst  = stage == 0 ? T1_OFF    : T2_OFF;
    const float* b_mv = stage == 0 ? gbo_b_mv : l1_b_mv;
    const float* b_s  = stage == 0 ? gbo_b_s  : l1_b_s;
    const int nt0 = 4*w + 2*jh;

    f32x4 acc[8], fac[2];
    #pragma unroll
    for (int j = 0; j < 8; ++j) acc[j] = f32x4{0.f,0.f,0.f,0.f};
    fac[0] = f32x4{0.f,0.f,0.f,0.f}; fac[1] = f32x4{0.f,0.f,0.f,0.f};

    if (jh == 0) mv_half<0>(acc, WB, lds, mvb, w, lane);
    else         mv_half<1>(acc, WB, lds, mvb, w, lane);

    if (stage == 0) {
      if (jh == 0) s_gemm<4,8>(acc[0], WB, lds, sab, s2mvb + w*2048, lane);
      #pragma unroll
      for (int i = 0; i < 2; ++i) {
        s_gemm<4,8>(fac[i], WB, lds, sab, s2sb + (nt0+i)*2048, lane);
        s_gemm<2,7>(fac[i], WB, lds, C0_OFF, ms2sb + (nt0+i)*1024, lane);
      }
    } else {
      if (jh == 0) s_gemm<8,9>(acc[0], WB, lds, sab, s2mvb + w*4096, lane);
      #pragma unroll
      for (int i = 0; i < 2; ++i) {
        s_gemm<8,9>(fac[i], WB, lds, sab, s2sb + (nt0+i)*4096, lane);
        s_gemm<2,7>(fac[i], WB, lds, C0_OFF, ms2sb + (nt0+i)*1024, lane);
      }
    }
    __syncthreads();

    if (jh == 0) {
      const float bm = b_mv[16*w + ol];
      #pragma unroll
      for (int r = 0; r < 4; ++r) acc[0][r] += bm;
    }
    #pragma unroll
    for (int i = 0; i < 2; ++i) {
      const float bs = b_s[16*(nt0+i) + ol];
      #pragma unroll
      for (int r = 0; r < 4; ++r) fac[i][r] += bs;
    }
    float sq[4], sm[4], s2[4];
    #pragma unroll
    for (int r = 0; r < 4; ++r) {
      sq[r] = (jh == 0)
        ? acc[0][r]*acc[0][r] + acc[2][r]*acc[2][r] + acc[3][r]*acc[3][r] + acc[4][r]*acc[4][r]
        : acc[0][r]*acc[0][r] + acc[1][r]*acc[1][r] + acc[2][r]*acc[2][r] + acc[6][r]*acc[6][r];
      sm[r] = fac[0][r] + fac[1][r];
      s2[r] = fac[0][r]*fac[0][r] + fac[1][r]*fac[1][r];
    }
    #pragma unroll
    for (int m = 1; m < 16; m <<= 1) {
      #pragma unroll
      for (int r = 0; r < 4; ++r) {
        sq[r] += __shfl_xor(sq[r], m);
        sm[r] += __shfl_xor(sm[r], m);
        s2[r] += __shfl_xor(s2[r], m);
      }
    }
    if (ol == 0) {
      #pragma unroll
      for (int r = 0; r < 4; ++r) {
        const int p = pg*4 + r;
        REDEQ[wv*16 + p] = sq[r]; REDS[wv*16 + p] = sm[r]; REDQ[wv*16 + p] = s2[r];
      }
    }
    __syncthreads();

    float rs[4], mu[4], rstd[4];
    #pragma unroll
    for (int r = 0; r < 4; ++r) {
      const int p = pg*4 + r;
      float te = 0.f, ts = 0.f, tq = 0.f;
      #pragma unroll
      for (int v2 = 0; v2 < 8; ++v2) { te += REDEQ[v2*16+p]; ts += REDS[v2*16+p]; tq += REDQ[v2*16+p]; }
      rs[r]   = 1.0f / sqrtf(fmaxf(te * (1.0f/64.0f), 0.01f));
      mu[r]   = ts * (1.0f/256.0f);
      rstd[r] = rsqrtf(tq * (1.0f/256.0f) - mu[r]*mu[r] + 1e-5f);
    }
    #pragma unroll
    for (int i = 0; i < 2; ++i) {
      #pragma unroll
      for (int r = 0; r < 4; ++r) {
        const int p = pg*4 + r, op = 16*(nt0+i) + ol;
        *(__bf16*)(lds + tdst + (p << 9) + swz(p, 2*op)) =
            (__bf16)gelu_t((fac[i][r] - mu[r]) * rstd[r]);
      }
    }
    if (jh == 0) {
      const int cnew = 16*w + ol;
      #pragma unroll
      for (int r = 0; r < 4; ++r) {
        const int p = pg*4 + r;
        const float a0n = acc[0][r] * rs[r];
        const float g   = gelu_t(a0n);
        GT[p*64 + cnew] = g;
        *(__bf16*)(lds + C0_OFF + (p<<7) + swz(p, 2*cnew)) = (__bf16)(g * a0n);
      }
    }
    __syncthreads();

    {
      const int cnew = 16*w + ol;
      float f[4];
      #pragma unroll
      for (int r = 0; r < 4; ++r) f[r] = rs[r] * GT[(pg*4+r)*64 + cnew];
      #pragma unroll
      for (int jl = 0; jl < 8; ++jl) {
        const int j = jh*8 + jl;
        #pragma unroll
        for (int r = 0; r < 4; ++r) {
          const int p = pg*4 + r;
          *(__bf16*)(lds + XA_OFF + (((j<<4)+p)<<7) + swz(p, 2*cnew)) = (__bf16)(acc[jl][r] * f[r]);
        }
      }
    }
    __syncthreads();
  }

  { // ---------------- stage D ----------------
    f32x4 acc[8], fac2;
    #pragma unroll
    for (int j = 0; j < 8; ++j) acc[j] = f32x4{0.f,0.f,0.f,0.f};
    fac2 = f32x4{0.f,0.f,0.f,0.f};

    if (jh == 0) mv_half<0>(acc, WB, lds, FB_MVD, w, lane);
    else         mv_half<1>(acc, WB, lds, FB_MVD, w, lane);
    if (jh == 0) s_gemm<8,9>(acc[0], WB, lds, T2_OFF, FB_S2MV_D + w*4096, lane);
    const int ntd = w + 4*jh;
    s_gemm<8,9>(fac2, WB, lds, T2_OFF, FB_S2S_D + ntd*4096, lane);
    s_gemm<2,7>(fac2, WB, lds, C0_OFF, FB_MS2S_D + ntd*1024, lane);

    if (jh == 0) {
      const float bm = l2_b_mv[16*w + ol];
      #pragma unroll
      for (int r = 0; r < 4; ++r) acc[0][r] += bm;
    }
    #pragma unroll
    for (int r = 0; r < 4; ++r) {
      const int p = pg*4 + r;
      float* dst = out + ((size_t)(n0 + p)*64 + 16*w + ol)*16 + jh*8;
      *(float4*)(dst+0) = make_float4(acc[0][r], acc[1][r], acc[2][r], acc[3][r]);
      *(float4*)(dst+4) = make_float4(acc[4][r], acc[5][r], acc[6][r], acc[7][r]);
    }
    {
      const int od = 16*ntd + ol;
      const float bs = l2_b_s[od];
      #pragma unroll
      for (int r = 0; r < 4; ++r) {
        const int p = pg*4 + r;
        out[SOFF + (size_t)(n0 + p)*128 + od] = fac2[r] + bs;
      }
    }
  }
}

// ============================ host launch ============================
extern "C" void kernel_launch(void* const* d_in, const int* in_sizes, int n_in,
                              void* d_out, int out_size, void* d_ws, size_t ws_size,
                              hipStream_t stream) {
  const float* xin          = (const float*)d_in[0];
  const float* sinp         = (const float*)d_in[1];
  const float* gb_w_mv      = (const float*)d_in[2];
  const float* gb_w_s2mv    = (const float*)d_in[3];
  const float* gb_b_mv      = (const float*)d_in[4];
  const float* gbo_w_mv     = (const float*)d_in[5];
  const float* gbo_w_s2mv   = (const float*)d_in[6];
  const float* gbo_b_mv     = (const float*)d_in[7];
  const float* gbo_w_mvs2s  = (const float*)d_in[8];
  const float* gbo_w_s2s    = (const float*)d_in[9];
  const float* gbo_b_s      = (const float*)d_in[10];
  const float* l1_w_mv      = (const float*)d_in[11];
  const float* l1_w_s2mv    = (const float*)d_in[12];
  const float* l1_b_mv      = (const float*)d_in[13];
  const float* l1_w_mvs2s   = (const float*)d_in[14];
  const float* l1_w_s2s     = (const float*)d_in[15];
  const float* l1_b_s       = (const float*)d_in[16];
  const float* l2_w_mv      = (const float*)d_in[17];
  const float* l2_w_s2mv    = (const float*)d_in[18];
  const float* l2_b_mv      = (const float*)d_in[19];
  const float* l2_w_mvs2s   = (const float*)d_in[20];
  const float* l2_w_s2s     = (const float*)d_in[21];
  const float* l2_b_s       = (const float*)d_in[22];
  unsigned short* WBu = (unsigned short*)d_ws;
  float* out = (float*)d_out;

  prep_bf<<<(TOT_BF + 255) / 256, 256, 0, stream>>>(
      gbo_w_mv, gbo_w_s2mv, gbo_w_mvs2s, gbo_w_s2s,
      l1_w_mv, l1_w_s2mv, l1_w_mvs2s, l1_w_s2s,
      l2_w_mv, l2_w_s2mv, l2_w_mvs2s, l2_w_s2s, WBu);

  prep_ga<<<(SA_TOT + 255) / 256, 256, 0, stream>>>(gb_w_mv, gb_w_s2mv, WBu);

  fused_all<<<NPTS / 16, 512, 0, stream>>>(
      xin, sinp, gb_b_mv, gbo_b_mv, gbo_b_s, l1_b_mv, l1_b_s,
      l2_b_mv, l2_b_s, WBu, out);
}

// Round 17
// 380.351 us; speedup vs baseline: 2.6460x; 1.0407x over previous
//
#include <hip/hip_runtime.h>
#include <math.h>

typedef __bf16 bf16x8 __attribute__((ext_vector_type(8)));
typedef float  f32x4  __attribute__((ext_vector_type(4)));

// ============================ constants ============================
constexpr int NPTS = 32768;
constexpr long long SOFF = 33554432LL;        // NPTS*64*16, start of scalar outputs

// ---- bf16 fragment region (all weights), element offsets in WBu ----
constexpr int TOT_BF   = 323584;
constexpr int FB_MVB    = 0;
constexpr int FB_MVC    = 36864;
constexpr int FB_MVD    = 73728;
constexpr int FB_S2MV_B = 110592;
constexpr int FB_S2MV_C = 118784;
constexpr int FB_S2MV_D = 135168;
constexpr int FB_S2S_B  = 151552;
constexpr int FB_S2S_C  = 184320;
constexpr int FB_S2S_D  = 249856;
constexpr int FB_MS2S_B = 282624;
constexpr int FB_MS2S_C = 299008;
constexpr int FB_MS2S_D = 315392;
// stage-A frags: hi at [SAW, SAW+SA_TOT), lo at [SAW+SA_TOT, SAW+2*SA_TOT)
constexpr int SAW      = 647168;
constexpr int GAS2_OFF = 73728;
constexpr int SA_TOT   = 90112;

// ---- fused LDS layout (bytes) ----
constexpr int XA_OFF  = 0;        // bf16 [16j][16p][64c] swizzled, 32768
constexpr int T1_OFF  = 36864;    // bf16 [16p][256] swizzled, 8192
constexpr int T2_OFF  = 45056;    // 8192
constexpr int C0_OFF  = 53248;    // bf16 [16p][64] swizzled, 2048
constexpr int GT_OFF  = 55296;    // f32 [16p][64o] gate, 4096
constexpr int RED_OFF = 59392;    // 3 x f32[8wv][16p] = 1536 (ends 60928)
constexpr int SA_OFF  = 65536;    // bf16 [16p][128] swizzled, 4096
constexpr int LDS_BYTES = 69632;  // 2 blocks/CU

// ==================== compile-time GA tables (GP/JOIN) ====================
namespace ga {
constexpr int MASK_OF[16] = {0,1,2,4,8,3,5,9,6,10,12,7,11,13,14,15};
constexpr int idx_of_mask(int m){ int r = 0; for(int i=0;i<16;++i) if(MASK_OF[i]==m) r=i; return r; }
constexpr int pcount(int x){ int c=0; while(x){ c += x&1; x >>= 1; } return c; }
constexpr int nswaps(int a,int b){ int s=0; a >>= 1; while(a){ s += pcount(a&b); a >>= 1; } return s; }
constexpr float rsign(int a,int b){ return (nswaps(a,b)&1) ? -1.0f : 1.0f; }
constexpr float dsign(int m){ return rsign(m, 15^m); }
struct Ent { int i, j, k; float s; };
struct GPT { Ent e[192]; };
constexpr GPT make_gp(){
  GPT t{}; int n=0;
  for(int i=0;i<16;++i) for(int j=0;j<16;++j){
    const int a=MASK_OF[i], b=MASK_OF[j];
    if((a & b & 1) != 0) continue;
    t.e[n].i=i; t.e[n].j=j; t.e[n].k=idx_of_mask(a^b); t.e[n].s=rsign(a,b); ++n;
  }
  return t;
}
struct JNT { Ent e[81]; };
constexpr JNT make_jn(){
  JNT t{}; int n=0;
  for(int i=0;i<16;++i) for(int j=0;j<16;++j){
    const int ci = 15 ^ MASK_OF[i], cj = 15 ^ MASK_OF[j];
    if((ci & cj) != 0) continue;
    const int mr = ci ^ cj, mk = 15 ^ mr;
    t.e[n].i=i; t.e[n].j=j; t.e[n].k=idx_of_mask(mk);
    t.e[n].s = dsign(MASK_OF[i]) * dsign(MASK_OF[j]) * rsign(ci,cj) * dsign(mk);
    ++n;
  }
  return t;
}
constexpr GPT GPt = make_gp();
constexpr JNT JNt = make_jn();
} // namespace ga

// ============================ helpers ============================
__device__ __forceinline__ float gelu_t(float x){
  const float u = 0.7978845608028654f * x * (1.0f + 0.044715f * x * x);
  return 0.5f * x * (1.0f + tanhf(u));
}
__device__ __forceinline__ int swz(int p, int byteoff){ return byteoff ^ ((p & 7) << 4); }

// ======================= prep: bcdm bf16 fragment weights =======================
__global__ void prep_bf(
    const float* __restrict__ gbo_w_mv, const float* __restrict__ gbo_w_s2mv,
    const float* __restrict__ gbo_w_mvs2s, const float* __restrict__ gbo_w_s2s,
    const float* __restrict__ l1_w_mv, const float* __restrict__ l1_w_s2mv,
    const float* __restrict__ l1_w_mvs2s, const float* __restrict__ l1_w_s2s,
    const float* __restrict__ l2_w_mv, const float* __restrict__ l2_w_s2mv,
    const float* __restrict__ l2_w_mvs2s, const float* __restrict__ l2_w_s2s,
    unsigned short* __restrict__ WBu)
{
  const int idx = blockIdx.x * 256 + threadIdx.x;
  if (idx >= TOT_BF) return;
  float v = 0.0f;
  if (idx < FB_S2MV_B) {
    const int st = idx / 36864, r2 = idx % 36864;
    const int k9 = r2 >> 12, r3 = r2 & 4095;
    const int nt = r3 >> 10, ks = (r3 >> 9) & 1, l = (r3 >> 3) & 63, e = r3 & 7;
    const int o = 16*nt + (l & 15), c = 32*ks + 8*(l >> 4) + e;
    const float* src = st==0 ? gbo_w_mv : (st==1 ? l1_w_mv : l2_w_mv);
    v = src[(o*64 + c)*9 + k9];
  } else if (idx < FB_S2S_B) {
    const float* src; int r, KS, KK;
    if (idx < FB_S2MV_C)      { r = idx - FB_S2MV_B; KS=4; KK=128; src=gbo_w_s2mv; }
    else if (idx < FB_S2MV_D) { r = idx - FB_S2MV_C; KS=8; KK=256; src=l1_w_s2mv; }
    else                      { r = idx - FB_S2MV_D; KS=8; KK=256; src=l2_w_s2mv; }
    const int per = KS*512, nt = r / per, r3 = r % per;
    const int ks = r3 >> 9, l = (r3 >> 3) & 63, e = r3 & 7;
    const int o = 16*nt + (l & 15), k = 32*ks + 8*(l >> 4) + e;
    v = src[o*KK + k];
  } else if (idx < FB_MS2S_B) {
    const float* src; int r, KS, KK;
    if (idx < FB_S2S_C)      { r = idx - FB_S2S_B; KS=4; KK=128; src=gbo_w_s2s; }
    else if (idx < FB_S2S_D) { r = idx - FB_S2S_C; KS=8; KK=256; src=l1_w_s2s; }
    else                     { r = idx - FB_S2S_D; KS=8; KK=256; src=l2_w_s2s; }
    const int per = KS*512, nt = r / per, r3 = r % per;
    const int ks = r3 >> 9, l = (r3 >> 3) & 63, e = r3 & 7;
    const int o = 16*nt + (l & 15), k = 32*ks + 8*(l >> 4) + e;
    v = src[o*KK + k];
  } else {
    const float* src; int r;
    if (idx < FB_MS2S_C)      { r = idx - FB_MS2S_B; src = gbo_w_mvs2s; }
    else if (idx < FB_MS2S_D) { r = idx - FB_MS2S_C; src = l1_w_mvs2s; }
    else                      { r = idx - FB_MS2S_D; src = l2_w_mvs2s; }
    const int nt = r >> 10, r3 = r & 1023;
    const int ks = r3 >> 9, l = (r3 >> 3) & 63, e = r3 & 7;
    const int o = 16*nt + (l & 15), k = 32*ks + 8*(l >> 4) + e;
    v = src[o*64 + k];
  }
  __bf16* WB = (__bf16*)WBu;
  const __bf16 h = (__bf16)v;
  WB[idx] = h;
  WB[TOT_BF + idx] = (__bf16)(v - (float)h);
}

// ======================= prep: stage-A bf16 fragments =======================
__global__ void prep_ga(const float* __restrict__ gb_w_mv,
                        const float* __restrict__ gb_w_s2mv,
                        unsigned short* __restrict__ WBu)
{
  const int idx = blockIdx.x * 256 + threadIdx.x;
  if (idx >= SA_TOT) return;
  float v;
  if (idx < GAS2_OFF) {                 // [9k][8nt][2ks][64l][8e]
    const int k9 = idx >> 13, r3 = idx & 8191;
    const int nt = r3 >> 10, ks = (r3 >> 9) & 1, l = (r3 >> 3) & 63, e = r3 & 7;
    const int o = 16*nt + (l & 15), c = 32*ks + 8*(l >> 4) + e;
    v = gb_w_mv[(o*64 + c)*9 + k9];
  } else {                              // [8nt][4ks][64l][8e]
    const int r = idx - GAS2_OFF;
    const int nt = r >> 11, ks = (r >> 9) & 3, l = (r >> 3) & 63, e = r & 7;
    const int o = 16*nt + (l & 15), k = 32*ks + 8*(l >> 4) + e;
    v = gb_w_s2mv[o*128 + k];
  }
  __bf16* WB = (__bf16*)WBu;
  const __bf16 h = (__bf16)v;
  WB[SAW + idx] = h;
  WB[SAW + SA_TOT + idx] = (__bf16)(v - (float)h);   // lo kept (unused this round)
}

// ======================= MFMA helpers =======================
template<int JH>
__device__ __forceinline__ void mv_half(f32x4 (&acc)[8], const __bf16* __restrict__ WB,
                                        const unsigned char* lds, int mvbase, int w, int lane)
{
  constexpr int GRa[2][8] = {{0,1,1,1,1,2,2,2},{2,2,2,3,3,3,3,4}};
  constexpr int PJa[2][8] = {{-1,0,-1,-1,-1,2,3,4},{-1,-1,-1,8,9,10,-1,14}};
  constexpr int KEa[2][8] = {{0,5,0,0,0,6,6,6},{0,0,0,7,7,7,0,8}};
  const int pa  = lane & 15;
  const int cb0 = (lane >> 4) << 4;
  const int wl8 = lane << 3;
  #pragma unroll
  for (int jl = 0; jl < 8; ++jl) {
    const int j = JH*8 + jl;
    #pragma unroll
    for (int ks = 0; ks < 2; ++ks) {
      bf16x8 a = *(const bf16x8*)(lds + XA_OFF + (((j<<4)+pa)<<7) + swz(pa, cb0 + (ks<<6)));
      const __bf16* bp = WB + mvbase + GRa[JH][jl]*4096 + (w<<10) + (ks<<9) + wl8;
      acc[jl] = __builtin_amdgcn_mfma_f32_16x16x32_bf16(a, *(const bf16x8*)bp, acc[jl], 0, 0, 0);
    }
    if (PJa[JH][jl] >= 0) {
      #pragma unroll
      for (int ks = 0; ks < 2; ++ks) {
        bf16x8 a = *(const bf16x8*)(lds + XA_OFF + (((PJa[JH][jl]<<4)+pa)<<7) + swz(pa, cb0 + (ks<<6)));
        const __bf16* bp = WB + mvbase + KEa[JH][jl]*4096 + (w<<10) + (ks<<9) + wl8;
        acc[jl] = __builtin_amdgcn_mfma_f32_16x16x32_bf16(a, *(const bf16x8*)bp, acc[jl], 0, 0, 0);
      }
    }
  }
}
template<int KS, int RSH>
__device__ __forceinline__ void s_gemm(f32x4& acc, const __bf16* __restrict__ WB,
                                       const unsigned char* lds, int abase, int wbase, int lane)
{
  const int pa  = lane & 15;
  const int cb0 = (lane >> 4) << 4;
  const int wl8 = lane << 3;
  #pragma unroll
  for (int ks = 0; ks < KS; ++ks) {
    bf16x8 a = *(const bf16x8*)(lds + abase + (pa << RSH) + swz(pa, cb0 + (ks << 6)));
    const __bf16* bp = WB + wbase + (ks << 9) + wl8;
    acc = __builtin_amdgcn_mfma_f32_16x16x32_bf16(a, *(const bf16x8*)bp, acc, 0, 0, 0);
  }
}

// ======================= fused_all: A + GP/JOIN + B/C/D =======================
// R17: phase A MFMA is now HI-ONLY (R16 spilled ~250MB: acc[16]=64 VGPR +
// hi+lo load pipeline > 128 cap). bcdm phases already hi-only and spill-free.
__global__ __launch_bounds__(512, 1) void fused_all(
    const float* __restrict__ xin,  const float* __restrict__ sinp,
    const float* __restrict__ gb_b_mv,
    const float* __restrict__ gbo_b_mv, const float* __restrict__ gbo_b_s,
    const float* __restrict__ l1_b_mv,  const float* __restrict__ l1_b_s,
    const float* __restrict__ l2_b_mv,  const float* __restrict__ l2_b_s,
    const unsigned short* __restrict__ WBu,
    float* __restrict__ out)
{
  __shared__ __align__(16) unsigned char lds[LDS_BYTES];
  const __bf16* WB = (const __bf16*)WBu;
  const int tid = threadIdx.x, lane = tid & 63, wv = tid >> 6;
  const int pg = lane >> 4, ol = lane & 15;
  const int n0 = blockIdx.x * 16;

  // ---------------- phase A: stage xin -> XA, sinp -> SA ----------------
  {
    const float4* src = (const float4*)(xin + (size_t)n0 * 1024);
    #pragma unroll
    for (int q = 0; q < 8; ++q) {
      const int i = q * 512 + tid;
      const float4 v = src[i];
      const int p = i >> 8, c = (i >> 2) & 63, j0 = (i & 3) << 2;
      const float vv[4] = {v.x, v.y, v.z, v.w};
      #pragma unroll
      for (int t = 0; t < 4; ++t)
        *(__bf16*)(lds + XA_OFF + ((((j0 + t) << 4) + p) << 7) + swz(p, 2 * c)) = (__bf16)vv[t];
    }
    {
      const float4 v = ((const float4*)(sinp + (size_t)n0 * 128))[tid];
      const int p = tid >> 5, k0 = (tid & 31) << 2;
      const float vv[4] = {v.x, v.y, v.z, v.w};
      #pragma unroll
      for (int t = 0; t < 4; ++t)
        *(__bf16*)(lds + SA_OFF + (p << 8) + swz(p, 2 * (k0 + t))) = (__bf16)vv[t];
    }
  }
  __syncthreads();

  // ---------------- phase A GEMM (hi-only), wave nt = rows [16nt,16nt+16) ----------------
  {
    const int nt = wv;
    f32x4 acc[16];
    #pragma unroll
    for (int j = 0; j < 16; ++j) acc[j] = f32x4{0.f,0.f,0.f,0.f};
    {
      constexpr int GR[16] = {0,1,1,1,1,2,2,2,2,2,2,3,3,3,3,4};
      constexpr int PJ[16] = {-1,0,-1,-1,-1,2,3,4,-1,-1,-1,8,9,10,-1,14};
      constexpr int KE[16] = {0,5,0,0,0,6,6,6,0,0,0,7,7,7,0,8};
      const int pa  = lane & 15;
      const int cb0 = (lane >> 4) << 4;
      const int wl8 = lane << 3;
      #pragma unroll
      for (int j = 0; j < 16; ++j) {
        #pragma unroll
        for (int ks = 0; ks < 2; ++ks) {
          bf16x8 a = *(const bf16x8*)(lds + XA_OFF + (((j<<4)+pa)<<7) + swz(pa, cb0 + (ks<<6)));
          const __bf16* bp = WB + SAW + GR[j]*8192 + (nt<<10) + (ks<<9) + wl8;
          acc[j] = __builtin_amdgcn_mfma_f32_16x16x32_bf16(a, *(const bf16x8*)bp, acc[j], 0, 0, 0);
        }
        if (PJ[j] >= 0) {
          #pragma unroll
          for (int ks = 0; ks < 2; ++ks) {
            bf16x8 a = *(const bf16x8*)(lds + XA_OFF + (((PJ[j]<<4)+pa)<<7) + swz(pa, cb0 + (ks<<6)));
            const __bf16* bp = WB + SAW + KE[j]*8192 + (nt<<10) + (ks<<9) + wl8;
            acc[j] = __builtin_amdgcn_mfma_f32_16x16x32_bf16(a, *(const bf16x8*)bp, acc[j], 0, 0, 0);
          }
        }
      }
      #pragma unroll
      for (int ks = 0; ks < 4; ++ks) {
        bf16x8 a = *(const bf16x8*)(lds + SA_OFF + (pa << 8) + swz(pa, cb0 + (ks << 6)));
        const __bf16* bp = WB + SAW + GAS2_OFF + (nt<<11) + (ks<<9) + wl8;
        acc[0] = __builtin_amdgcn_mfma_f32_16x16x32_bf16(a, *(const bf16x8*)bp, acc[0], 0, 0, 0);
      }
      const float bm = gb_b_mv[16*nt + ol];
      #pragma unroll
      for (int r = 0; r < 4; ++r) acc[0][r] += bm;
    }
    __syncthreads();                   // XA reads complete -> overlay HT

    { // write HT bf16 [16p][128 rows][16j], row at p*4096 + (o*32 ^ ((o&12)<<3))
      const int o = 16*nt + ol;
      const int obase = (o * 32) ^ ((o & 12) << 3);
      #pragma unroll
      for (int r = 0; r < 4; ++r) {
        const int p = pg*4 + r;
        bf16x8 h0, h1;
        #pragma unroll
        for (int j = 0; j < 8; ++j) { h0[j] = (__bf16)acc[j][r]; h1[j] = (__bf16)acc[8+j][r]; }
        *(bf16x8*)(lds + (p << 12) + obase)      = h0;
        *(bf16x8*)(lds + (p << 12) + obase + 16) = h1;
      }
    }
  }
  __syncthreads();

  // ---------------- GP + JOIN into registers ----------------
  float gpo[16], jno[16];
  {
    const int p2 = tid >> 5, ch = tid & 31;
    float L[16], R[16];
    auto ldrow = [&](int row, float* X){
      const unsigned char* q = lds + (p2 << 12) + ((row * 32) ^ ((row & 12) << 3));
      bf16x8 a = *(const bf16x8*)q, b = *(const bf16x8*)(q + 16);
      #pragma unroll
      for (int t = 0; t < 8; ++t) { X[t] = (float)a[t]; X[8+t] = (float)b[t]; }
    };
    ldrow(ch, L); ldrow(32 + ch, R);
    #pragma unroll
    for (int j = 0; j < 16; ++j) gpo[j] = 0.0f;
    #pragma unroll
    for (int n = 0; n < 192; ++n)
      gpo[ga::GPt.e[n].k] = fmaf(ga::GPt.e[n].s * L[ga::GPt.e[n].i], R[ga::GPt.e[n].j], gpo[ga::GPt.e[n].k]);
    ldrow(64 + ch, L); ldrow(96 + ch, R);
    #pragma unroll
    for (int j = 0; j < 16; ++j) jno[j] = 0.0f;
    #pragma unroll
    for (int n = 0; n < 81; ++n)
      jno[ga::JNt.e[n].k] = fmaf(ga::JNt.e[n].s * L[ga::JNt.e[n].i], R[ga::JNt.e[n].j], jno[ga::JNt.e[n].k]);
  }
  __syncthreads();                     // HT reads complete -> overlay XA/C0

  { // write hidden -> XA bf16 [16j][16p][64c] + C0
    const int p2 = tid >> 5, ch = tid & 31;
    #pragma unroll
    for (int j = 0; j < 16; ++j) {
      *(__bf16*)(lds + XA_OFF + (((j<<4)+p2)<<7) + swz(p2, 2*ch))      = (__bf16)gpo[j];
      *(__bf16*)(lds + XA_OFF + (((j<<4)+p2)<<7) + swz(p2, 2*(32+ch))) = (__bf16)jno[j];
    }
    *(__bf16*)(lds + C0_OFF + (p2<<7) + swz(p2, 2*ch))      = (__bf16)gpo[0];
    *(__bf16*)(lds + C0_OFF + (p2<<7) + swz(p2, 2*(32+ch))) = (__bf16)jno[0];
  }
  __syncthreads();

  // ---------------- phases B, C, D (hi-only) ----------------
  const int w = wv & 3, jh = wv >> 2;
  float* REDEQ = (float*)(lds + RED_OFF);        // [8][16]
  float* REDS  = REDEQ + 128;
  float* REDQ  = REDEQ + 256;
  float* GT    = (float*)(lds + GT_OFF);         // [16p][64o]

  #pragma unroll 1
  for (int stage = 0; stage < 2; ++stage) {
    const int mvb   = stage == 0 ? FB_MVB    : FB_MVC;
    const int s2mvb = stage == 0 ? FB_S2MV_B : FB_S2MV_C;
    const int s2sb  = stage == 0 ? FB_S2S_B  : FB_S2S_C;
    const int ms2sb = stage == 0 ? FB_MS2S_B : FB_MS2S_C;
    const int sab   = stage == 0 ? SA_OFF    : T1_OFF;
    const int tdst  = stage == 0 ? T1_OFF    : T2_OFF;
    const float* b_mv = stage == 0 ? gbo_b_mv : l1_b_mv;
    const float* b_s  = stage == 0 ? gbo_b_s  : l1_b_s;
    const int nt0 = 4*w + 2*jh;

    f32x4 acc[8], fac[2];
    #pragma unroll
    for (int j = 0; j < 8; ++j) acc[j] = f32x4{0.f,0.f,0.f,0.f};
    fac[0] = f32x4{0.f,0.f,0.f,0.f}; fac[1] = f32x4{0.f,0.f,0.f,0.f};

    if (jh == 0) mv_half<0>(acc, WB, lds, mvb, w, lane);
    else         mv_half<1>(acc, WB, lds, mvb, w, lane);

    if (stage == 0) {
      if (jh == 0) s_gemm<4,8>(acc[0], WB, lds, sab, s2mvb + w*2048, lane);
      #pragma unroll
      for (int i = 0; i < 2; ++i) {
        s_gemm<4,8>(fac[i], WB, lds, sab, s2sb + (nt0+i)*2048, lane);
        s_gemm<2,7>(fac[i], WB, lds, C0_OFF, ms2sb + (nt0+i)*1024, lane);
      }
    } else {
      if (jh == 0) s_gemm<8,9>(acc[0], WB, lds, sab, s2mvb + w*4096, lane);
      #pragma unroll
      for (int i = 0; i < 2; ++i) {
        s_gemm<8,9>(fac[i], WB, lds, sab, s2sb + (nt0+i)*4096, lane);
        s_gemm<2,7>(fac[i], WB, lds, C0_OFF, ms2sb + (nt0+i)*1024, lane);
      }
    }
    __syncthreads();

    if (jh == 0) {
      const float bm = b_mv[16*w + ol];
      #pragma unroll
      for (int r = 0; r < 4; ++r) acc[0][r] += bm;
    }
    #pragma unroll
    for (int i = 0; i < 2; ++i) {
      const float bs = b_s[16*(nt0+i) + ol];
      #pragma unroll
      for (int r = 0; r < 4; ++r) fac[i][r] += bs;
    }
    float sq[4], sm[4], s2[4];
    #pragma unroll
    for (int r = 0; r < 4; ++r) {
      sq[r] = (jh == 0)
        ? acc[0][r]*acc[0][r] + acc[2][r]*acc[2][r] + acc[3][r]*acc[3][r] + acc[4][r]*acc[4][r]
        : acc[0][r]*acc[0][r] + acc[1][r]*acc[1][r] + acc[2][r]*acc[2][r] + acc[6][r]*acc[6][r];
      sm[r] = fac[0][r] + fac[1][r];
      s2[r] = fac[0][r]*fac[0][r] + fac[1][r]*fac[1][r];
    }
    #pragma unroll
    for (int m = 1; m < 16; m <<= 1) {
      #pragma unroll
      for (int r = 0; r < 4; ++r) {
        sq[r] += __shfl_xor(sq[r], m);
        sm[r] += __shfl_xor(sm[r], m);
        s2[r] += __shfl_xor(s2[r], m);
      }
    }
    if (ol == 0) {
      #pragma unroll
      for (int r = 0; r < 4; ++r) {
        const int p = pg*4 + r;
        REDEQ[wv*16 + p] = sq[r]; REDS[wv*16 + p] = sm[r]; REDQ[wv*16 + p] = s2[r];
      }
    }
    __syncthreads();

    float rs[4], mu[4], rstd[4];
    #pragma unroll
    for (int r = 0; r < 4; ++r) {
      const int p = pg*4 + r;
      float te = 0.f, ts = 0.f, tq = 0.f;
      #pragma unroll
      for (int v2 = 0; v2 < 8; ++v2) { te += REDEQ[v2*16+p]; ts += REDS[v2*16+p]; tq += REDQ[v2*16+p]; }
      rs[r]   = 1.0f / sqrtf(fmaxf(te * (1.0f/64.0f), 0.01f));
      mu[r]   = ts * (1.0f/256.0f);
      rstd[r] = rsqrtf(tq * (1.0f/256.0f) - mu[r]*mu[r] + 1e-5f);
    }
    #pragma unroll
    for (int i = 0; i < 2; ++i) {
      #pragma unroll
      for (int r = 0; r < 4; ++r) {
        const int p = pg*4 + r, op = 16*(nt0+i) + ol;
        *(__bf16*)(lds + tdst + (p << 9) + swz(p, 2*op)) =
            (__bf16)gelu_t((fac[i][r] - mu[r]) * rstd[r]);
      }
    }
    if (jh == 0) {
      const int cnew = 16*w + ol;
      #pragma unroll
      for (int r = 0; r < 4; ++r) {
        const int p = pg*4 + r;
        const float a0n = acc[0][r] * rs[r];
        const float g   = gelu_t(a0n);
        GT[p*64 + cnew] = g;
        *(__bf16*)(lds + C0_OFF + (p<<7) + swz(p, 2*cnew)) = (__bf16)(g * a0n);
      }
    }
    __syncthreads();

    {
      const int cnew = 16*w + ol;
      float f[4];
      #pragma unroll
      for (int r = 0; r < 4; ++r) f[r] = rs[r] * GT[(pg*4+r)*64 + cnew];
      #pragma unroll
      for (int jl = 0; jl < 8; ++jl) {
        const int j = jh*8 + jl;
        #pragma unroll
        for (int r = 0; r < 4; ++r) {
          const int p = pg*4 + r;
          *(__bf16*)(lds + XA_OFF + (((j<<4)+p)<<7) + swz(p, 2*cnew)) = (__bf16)(acc[jl][r] * f[r]);
        }
      }
    }
    __syncthreads();
  }

  { // ---------------- stage D ----------------
    f32x4 acc[8], fac2;
    #pragma unroll
    for (int j = 0; j < 8; ++j) acc[j] = f32x4{0.f,0.f,0.f,0.f};
    fac2 = f32x4{0.f,0.f,0.f,0.f};

    if (jh == 0) mv_half<0>(acc, WB, lds, FB_MVD, w, lane);
    else         mv_half<1>(acc, WB, lds, FB_MVD, w, lane);
    if (jh == 0) s_gemm<8,9>(acc[0], WB, lds, T2_OFF, FB_S2MV_D + w*4096, lane);
    const int ntd = w + 4*jh;
    s_gemm<8,9>(fac2, WB, lds, T2_OFF, FB_S2S_D + ntd*4096, lane);
    s_gemm<2,7>(fac2, WB, lds, C0_OFF, FB_MS2S_D + ntd*1024, lane);

    if (jh == 0) {
      const float bm = l2_b_mv[16*w + ol];
      #pragma unroll
      for (int r = 0; r < 4; ++r) acc[0][r] += bm;
    }
    #pragma unroll
    for (int r = 0; r < 4; ++r) {
      const int p = pg*4 + r;
      float* dst = out + ((size_t)(n0 + p)*64 + 16*w + ol)*16 + jh*8;
      *(float4*)(dst+0) = make_float4(acc[0][r], acc[1][r], acc[2][r], acc[3][r]);
      *(float4*)(dst+4) = make_float4(acc[4][r], acc[5][r], acc[6][r], acc[7][r]);
    }
    {
      const int od = 16*ntd + ol;
      const float bs = l2_b_s[od];
      #pragma unroll
      for (int r = 0; r < 4; ++r) {
        const int p = pg*4 + r;
        out[SOFF + (size_t)(n0 + p)*128 + od] = fac2[r] + bs;
      }
    }
  }
}

// ============================ host launch ============================
extern "C" void kernel_launch(void* const* d_in, const int* in_sizes, int n_in,
                              void* d_out, int out_size, void* d_ws, size_t ws_size,
                              hipStream_t stream) {
  const float* xin          = (const float*)d_in[0];
  const float* sinp         = (const float*)d_in[1];
  const float* gb_w_mv      = (const float*)d_in[2];
  const float* gb_w_s2mv    = (const float*)d_in[3];
  const float* gb_b_mv      = (const float*)d_in[4];
  const float* gbo_w_mv     = (const float*)d_in[5];
  const float* gbo_w_s2mv   = (const float*)d_in[6];
  const float* gbo_b_mv     = (const float*)d_in[7];
  const float* gbo_w_mvs2s  = (const float*)d_in[8];
  const float* gbo_w_s2s    = (const float*)d_in[9];
  const float* gbo_b_s      = (const float*)d_in[10];
  const float* l1_w_mv      = (const float*)d_in[11];
  const float* l1_w_s2mv    = (const float*)d_in[12];
  const float* l1_b_mv      = (const float*)d_in[13];
  const float* l1_w_mvs2s   = (const float*)d_in[14];
  const float* l1_w_s2s     = (const float*)d_in[15];
  const float* l1_b_s       = (const float*)d_in[16];
  const float* l2_w_mv      = (const float*)d_in[17];
  const float* l2_w_s2mv    = (const float*)d_in[18];
  const float* l2_b_mv      = (const float*)d_in[19];
  const float* l2_w_mvs2s   = (const float*)d_in[20];
  const float* l2_w_s2s     = (const float*)d_in[21];
  const float* l2_b_s       = (const float*)d_in[22];
  unsigned short* WBu = (unsigned short*)d_ws;
  float* out = (float*)d_out;

  prep_bf<<<(TOT_BF + 255) / 256, 256, 0, stream>>>(
      gbo_w_mv, gbo_w_s2mv, gbo_w_mvs2s, gbo_w_s2s,
      l1_w_mv, l1_w_s2mv, l1_w_mvs2s, l1_w_s2s,
      l2_w_mv, l2_w_s2mv, l2_w_mvs2s, l2_w_s2s, WBu);

  prep_ga<<<(SA_TOT + 255) / 256, 256, 0, stream>>>(gb_w_mv, gb_w_s2mv, WBu);

  fused_all<<<NPTS / 16, 512, 0, stream>>>(
      xin, sinp, gb_b_mv, gbo_b_mv, gbo_b_s, l1_b_mv, l1_b_s,
      l2_b_mv, l2_b_s, WBu, out);
}

// Round 18
// 376.881 us; speedup vs baseline: 2.6704x; 1.0092x over previous
//
#include <hip/hip_runtime.h>
#include <math.h>

typedef __bf16 bf16x8 __attribute__((ext_vector_type(8)));
typedef float  f32x4  __attribute__((ext_vector_type(4)));

// ============================ constants ============================
constexpr int NPTS = 32768;
constexpr long long SOFF = 33554432LL;        // NPTS*64*16, start of scalar outputs

// ---- bf16 fragment region (all weights), element offsets in WBu ----
constexpr int TOT_BF   = 323584;
constexpr int FB_MVB    = 0;
constexpr int FB_MVC    = 36864;
constexpr int FB_MVD    = 73728;
constexpr int FB_S2MV_B = 110592;
constexpr int FB_S2MV_C = 118784;
constexpr int FB_S2MV_D = 135168;
constexpr int FB_S2S_B  = 151552;
constexpr int FB_S2S_C  = 184320;
constexpr int FB_S2S_D  = 249856;
constexpr int FB_MS2S_B = 282624;
constexpr int FB_MS2S_C = 299008;
constexpr int FB_MS2S_D = 315392;
// stage-A frags: hi at [SAW, SAW+SA_TOT), lo at [SAW+SA_TOT, SAW+2*SA_TOT)
constexpr int SAW      = 647168;
constexpr int GAS2_OFF = 73728;
constexpr int SA_TOT   = 90112;

// ---- fused LDS layout (bytes) ----
constexpr int XA_OFF  = 0;        // bf16 [16j][16p][64c] swizzled, 32768
constexpr int HT0_OFF = 32768;    // bf16 [16p][128 rows][8j(0-7)] 16B rows, 32768
// HT1 (j8-15) overlays XA at [0,32768) after phase-A reads complete
constexpr int T1_OFF  = 36864;    // bf16 [16p][256] swizzled, 8192
constexpr int T2_OFF  = 45056;    // 8192
constexpr int C0_OFF  = 53248;    // bf16 [16p][64] swizzled, 2048
constexpr int GT_OFF  = 55296;    // f32 [16p][64o] gate, 4096
constexpr int RED_OFF = 59392;    // 3 x f32[8wv][16p] = 1536 (ends 60928)
constexpr int SA_OFF  = 65536;    // bf16 [16p][128] swizzled, 4096
constexpr int LDS_BYTES = 69632;  // 2 blocks/CU

// ==================== compile-time GA tables (GP/JOIN) ====================
namespace ga {
constexpr int MASK_OF[16] = {0,1,2,4,8,3,5,9,6,10,12,7,11,13,14,15};
constexpr int idx_of_mask(int m){ int r = 0; for(int i=0;i<16;++i) if(MASK_OF[i]==m) r=i; return r; }
constexpr int pcount(int x){ int c=0; while(x){ c += x&1; x >>= 1; } return c; }
constexpr int nswaps(int a,int b){ int s=0; a >>= 1; while(a){ s += pcount(a&b); a >>= 1; } return s; }
constexpr float rsign(int a,int b){ return (nswaps(a,b)&1) ? -1.0f : 1.0f; }
constexpr float dsign(int m){ return rsign(m, 15^m); }
struct Ent { int i, j, k; float s; };
struct GPT { Ent e[192]; };
constexpr GPT make_gp(){
  GPT t{}; int n=0;
  for(int i=0;i<16;++i) for(int j=0;j<16;++j){
    const int a=MASK_OF[i], b=MASK_OF[j];
    if((a & b & 1) != 0) continue;
    t.e[n].i=i; t.e[n].j=j; t.e[n].k=idx_of_mask(a^b); t.e[n].s=rsign(a,b); ++n;
  }
  return t;
}
struct JNT { Ent e[81]; };
constexpr JNT make_jn(){
  JNT t{}; int n=0;
  for(int i=0;i<16;++i) for(int j=0;j<16;++j){
    const int ci = 15 ^ MASK_OF[i], cj = 15 ^ MASK_OF[j];
    if((ci & cj) != 0) continue;
    const int mr = ci ^ cj, mk = 15 ^ mr;
    t.e[n].i=i; t.e[n].j=j; t.e[n].k=idx_of_mask(mk);
    t.e[n].s = dsign(MASK_OF[i]) * dsign(MASK_OF[j]) * rsign(ci,cj) * dsign(mk);
    ++n;
  }
  return t;
}
constexpr GPT GPt = make_gp();
constexpr JNT JNt = make_jn();
} // namespace ga

// ============================ helpers ============================
__device__ __forceinline__ float gelu_t(float x){
  const float u = 0.7978845608028654f * x * (1.0f + 0.044715f * x * x);
  return 0.5f * x * (1.0f + tanhf(u));
}
__device__ __forceinline__ int swz(int p, int byteoff){ return byteoff ^ ((p & 7) << 4); }
// HT half row address: 16B row per (p,o)
__device__ __forceinline__ int htaddr(int p, int o){ return (p << 11) + ((o * 16) ^ ((p & 7) << 4)); }

// ======================= prep: bcdm bf16 fragment weights =======================
__global__ void prep_bf(
    const float* __restrict__ gbo_w_mv, const float* __restrict__ gbo_w_s2mv,
    const float* __restrict__ gbo_w_mvs2s, const float* __restrict__ gbo_w_s2s,
    const float* __restrict__ l1_w_mv, const float* __restrict__ l1_w_s2mv,
    const float* __restrict__ l1_w_mvs2s, const float* __restrict__ l1_w_s2s,
    const float* __restrict__ l2_w_mv, const float* __restrict__ l2_w_s2mv,
    const float* __restrict__ l2_w_mvs2s, const float* __restrict__ l2_w_s2s,
    unsigned short* __restrict__ WBu)
{
  const int idx = blockIdx.x * 256 + threadIdx.x;
  if (idx >= TOT_BF) return;
  float v = 0.0f;
  if (idx < FB_S2MV_B) {
    const int st = idx / 36864, r2 = idx % 36864;
    const int k9 = r2 >> 12, r3 = r2 & 4095;
    const int nt = r3 >> 10, ks = (r3 >> 9) & 1, l = (r3 >> 3) & 63, e = r3 & 7;
    const int o = 16*nt + (l & 15), c = 32*ks + 8*(l >> 4) + e;
    const float* src = st==0 ? gbo_w_mv : (st==1 ? l1_w_mv : l2_w_mv);
    v = src[(o*64 + c)*9 + k9];
  } else if (idx < FB_S2S_B) {
    const float* src; int r, KS, KK;
    if (idx < FB_S2MV_C)      { r = idx - FB_S2MV_B; KS=4; KK=128; src=gbo_w_s2mv; }
    else if (idx < FB_S2MV_D) { r = idx - FB_S2MV_C; KS=8; KK=256; src=l1_w_s2mv; }
    else                      { r = idx - FB_S2MV_D; KS=8; KK=256; src=l2_w_s2mv; }
    const int per = KS*512, nt = r / per, r3 = r % per;
    const int ks = r3 >> 9, l = (r3 >> 3) & 63, e = r3 & 7;
    const int o = 16*nt + (l & 15), k = 32*ks + 8*(l >> 4) + e;
    v = src[o*KK + k];
  } else if (idx < FB_MS2S_B) {
    const float* src; int r, KS, KK;
    if (idx < FB_S2S_C)      { r = idx - FB_S2S_B; KS=4; KK=128; src=gbo_w_s2s; }
    else if (idx < FB_S2S_D) { r = idx - FB_S2S_C; KS=8; KK=256; src=l1_w_s2s; }
    else                     { r = idx - FB_S2S_D; KS=8; KK=256; src=l2_w_s2s; }
    const int per = KS*512, nt = r / per, r3 = r % per;
    const int ks = r3 >> 9, l = (r3 >> 3) & 63, e = r3 & 7;
    const int o = 16*nt + (l & 15), k = 32*ks + 8*(l >> 4) + e;
    v = src[o*KK + k];
  } else {
    const float* src; int r;
    if (idx < FB_MS2S_C)      { r = idx - FB_MS2S_B; src = gbo_w_mvs2s; }
    else if (idx < FB_MS2S_D) { r = idx - FB_MS2S_C; src = l1_w_mvs2s; }
    else                      { r = idx - FB_MS2S_D; src = l2_w_mvs2s; }
    const int nt = r >> 10, r3 = r & 1023;
    const int ks = r3 >> 9, l = (r3 >> 3) & 63, e = r3 & 7;
    const int o = 16*nt + (l & 15), k = 32*ks + 8*(l >> 4) + e;
    v = src[o*64 + k];
  }
  __bf16* WB = (__bf16*)WBu;
  const __bf16 h = (__bf16)v;
  WB[idx] = h;
  WB[TOT_BF + idx] = (__bf16)(v - (float)h);
}

// ======================= prep: stage-A bf16 fragments =======================
__global__ void prep_ga(const float* __restrict__ gb_w_mv,
                        const float* __restrict__ gb_w_s2mv,
                        unsigned short* __restrict__ WBu)
{
  const int idx = blockIdx.x * 256 + threadIdx.x;
  if (idx >= SA_TOT) return;
  float v;
  if (idx < GAS2_OFF) {                 // [9k][8nt][2ks][64l][8e]
    const int k9 = idx >> 13, r3 = idx & 8191;
    const int nt = r3 >> 10, ks = (r3 >> 9) & 1, l = (r3 >> 3) & 63, e = r3 & 7;
    const int o = 16*nt + (l & 15), c = 32*ks + 8*(l >> 4) + e;
    v = gb_w_mv[(o*64 + c)*9 + k9];
  } else {                              // [8nt][4ks][64l][8e]
    const int r = idx - GAS2_OFF;
    const int nt = r >> 11, ks = (r >> 9) & 3, l = (r >> 3) & 63, e = r & 7;
    const int o = 16*nt + (l & 15), k = 32*ks + 8*(l >> 4) + e;
    v = gb_w_s2mv[o*128 + k];
  }
  __bf16* WB = (__bf16*)WBu;
  const __bf16 h = (__bf16)v;
  WB[SAW + idx] = h;
  WB[SAW + SA_TOT + idx] = (__bf16)(v - (float)h);   // lo kept (unused)
}

// ======================= MFMA helpers =======================
// Phase-A half-pass: blades PASS*8..PASS*8+7, acc[8] (32 VGPR max live).
template<int PASS>
__device__ __forceinline__ void ga_half(f32x4 (&acc)[8], const __bf16* __restrict__ WB,
                                        const unsigned char* lds, int nt, int lane)
{
  constexpr int GR[16] = {0,1,1,1,1,2,2,2,2,2,2,3,3,3,3,4};
  constexpr int PJ[16] = {-1,0,-1,-1,-1,2,3,4,-1,-1,-1,8,9,10,-1,14};
  constexpr int KE[16] = {0,5,0,0,0,6,6,6,0,0,0,7,7,7,0,8};
  const int pa  = lane & 15;
  const int cb0 = (lane >> 4) << 4;
  const int wl8 = lane << 3;
  #pragma unroll
  for (int jl = 0; jl < 8; ++jl) {
    const int j = PASS*8 + jl;
    #pragma unroll
    for (int ks = 0; ks < 2; ++ks) {
      bf16x8 a = *(const bf16x8*)(lds + XA_OFF + (((j<<4)+pa)<<7) + swz(pa, cb0 + (ks<<6)));
      const __bf16* bp = WB + SAW + GR[j]*8192 + (nt<<10) + (ks<<9) + wl8;
      acc[jl] = __builtin_amdgcn_mfma_f32_16x16x32_bf16(a, *(const bf16x8*)bp, acc[jl], 0, 0, 0);
    }
    if (PJ[j] >= 0) {
      #pragma unroll
      for (int ks = 0; ks < 2; ++ks) {
        bf16x8 a = *(const bf16x8*)(lds + XA_OFF + (((PJ[j]<<4)+pa)<<7) + swz(pa, cb0 + (ks<<6)));
        const __bf16* bp = WB + SAW + KE[j]*8192 + (nt<<10) + (ks<<9) + wl8;
        acc[jl] = __builtin_amdgcn_mfma_f32_16x16x32_bf16(a, *(const bf16x8*)bp, acc[jl], 0, 0, 0);
      }
    }
  }
}
template<int JH>
__device__ __forceinline__ void mv_half(f32x4 (&acc)[8], const __bf16* __restrict__ WB,
                                        const unsigned char* lds, int mvbase, int w, int lane)
{
  constexpr int GRa[2][8] = {{0,1,1,1,1,2,2,2},{2,2,2,3,3,3,3,4}};
  constexpr int PJa[2][8] = {{-1,0,-1,-1,-1,2,3,4},{-1,-1,-1,8,9,10,-1,14}};
  constexpr int KEa[2][8] = {{0,5,0,0,0,6,6,6},{0,0,0,7,7,7,0,8}};
  const int pa  = lane & 15;
  const int cb0 = (lane >> 4) << 4;
  const int wl8 = lane << 3;
  #pragma unroll
  for (int jl = 0; jl < 8; ++jl) {
    const int j = JH*8 + jl;
    #pragma unroll
    for (int ks = 0; ks < 2; ++ks) {
      bf16x8 a = *(const bf16x8*)(lds + XA_OFF + (((j<<4)+pa)<<7) + swz(pa, cb0 + (ks<<6)));
      const __bf16* bp = WB + mvbase + GRa[JH][jl]*4096 + (w<<10) + (ks<<9) + wl8;
      acc[jl] = __builtin_amdgcn_mfma_f32_16x16x32_bf16(a, *(const bf16x8*)bp, acc[jl], 0, 0, 0);
    }
    if (PJa[JH][jl] >= 0) {
      #pragma unroll
      for (int ks = 0; ks < 2; ++ks) {
        bf16x8 a = *(const bf16x8*)(lds + XA_OFF + (((PJa[JH][jl]<<4)+pa)<<7) + swz(pa, cb0 + (ks<<6)));
        const __bf16* bp = WB + mvbase + KEa[JH][jl]*4096 + (w<<10) + (ks<<9) + wl8;
        acc[jl] = __builtin_amdgcn_mfma_f32_16x16x32_bf16(a, *(const bf16x8*)bp, acc[jl], 0, 0, 0);
      }
    }
  }
}
template<int KS, int RSH>
__device__ __forceinline__ void s_gemm(f32x4& acc, const __bf16* __restrict__ WB,
                                       const unsigned char* lds, int abase, int wbase, int lane)
{
  const int pa  = lane & 15;
  const int cb0 = (lane >> 4) << 4;
  const int wl8 = lane << 3;
  #pragma unroll
  for (int ks = 0; ks < KS; ++ks) {
    bf16x8 a = *(const bf16x8*)(lds + abase + (pa << RSH) + swz(pa, cb0 + (ks << 6)));
    const __bf16* bp = WB + wbase + (ks << 9) + wl8;
    acc = __builtin_amdgcn_mfma_f32_16x16x32_bf16(a, *(const bf16x8*)bp, acc, 0, 0, 0);
  }
}

// ======================= fused_all: A + GP/JOIN + B/C/D =======================
// R18: phase A split into two 8-blade passes (acc[8] not acc[16]) -- R16/R17
// both spilled exactly 250B/thread = acc[16] store/reload at cap 128.
// HT0 (j0-7) at [32768,65536) written pre-barrier; HT1 (j8-15) overlays XA.
__global__ __launch_bounds__(512, 1) void fused_all(
    const float* __restrict__ xin,  const float* __restrict__ sinp,
    const float* __restrict__ gb_b_mv,
    const float* __restrict__ gbo_b_mv, const float* __restrict__ gbo_b_s,
    const float* __restrict__ l1_b_mv,  const float* __restrict__ l1_b_s,
    const float* __restrict__ l2_b_mv,  const float* __restrict__ l2_b_s,
    const unsigned short* __restrict__ WBu,
    float* __restrict__ out)
{
  __shared__ __align__(16) unsigned char lds[LDS_BYTES];
  const __bf16* WB = (const __bf16*)WBu;
  const int tid = threadIdx.x, lane = tid & 63, wv = tid >> 6;
  const int pg = lane >> 4, ol = lane & 15;
  const int n0 = blockIdx.x * 16;

  // ---------------- stage xin -> XA, sinp -> SA ----------------
  {
    const float4* src = (const float4*)(xin + (size_t)n0 * 1024);
    #pragma unroll
    for (int q = 0; q < 8; ++q) {
      const int i = q * 512 + tid;
      const float4 v = src[i];
      const int p = i >> 8, c = (i >> 2) & 63, j0 = (i & 3) << 2;
      const float vv[4] = {v.x, v.y, v.z, v.w};
      #pragma unroll
      for (int t = 0; t < 4; ++t)
        *(__bf16*)(lds + XA_OFF + ((((j0 + t) << 4) + p) << 7) + swz(p, 2 * c)) = (__bf16)vv[t];
    }
    {
      const float4 v = ((const float4*)(sinp + (size_t)n0 * 128))[tid];
      const int p = tid >> 5, k0 = (tid & 31) << 2;
      const float vv[4] = {v.x, v.y, v.z, v.w};
      #pragma unroll
      for (int t = 0; t < 4; ++t)
        *(__bf16*)(lds + SA_OFF + (p << 8) + swz(p, 2 * (k0 + t))) = (__bf16)vv[t];
    }
  }
  __syncthreads();

  // ---------------- phase A GEMM: two 8-blade passes ----------------
  {
    const int nt = wv;
    const int o = 16*nt + ol;
    // pass 0: blades 0..7 (+ s2mv + bias on j0) -> HT0 (disjoint from XA)
    {
      f32x4 acc[8];
      #pragma unroll
      for (int j = 0; j < 8; ++j) acc[j] = f32x4{0.f,0.f,0.f,0.f};
      ga_half<0>(acc, WB, lds, nt, lane);
      {
        const int pa  = lane & 15;
        const int cb0 = (lane >> 4) << 4;
        const int wl8 = lane << 3;
        #pragma unroll
        for (int ks = 0; ks < 4; ++ks) {
          bf16x8 a = *(const bf16x8*)(lds + SA_OFF + (pa << 8) + swz(pa, cb0 + (ks << 6)));
          const __bf16* bp = WB + SAW + GAS2_OFF + (nt<<11) + (ks<<9) + wl8;
          acc[0] = __builtin_amdgcn_mfma_f32_16x16x32_bf16(a, *(const bf16x8*)bp, acc[0], 0, 0, 0);
        }
        const float bm = gb_b_mv[o];
        #pragma unroll
        for (int r = 0; r < 4; ++r) acc[0][r] += bm;
      }
      #pragma unroll
      for (int r = 0; r < 4; ++r) {
        const int p = pg*4 + r;
        bf16x8 h0;
        #pragma unroll
        for (int j = 0; j < 8; ++j) h0[j] = (__bf16)acc[j][r];
        *(bf16x8*)(lds + HT0_OFF + htaddr(p, o)) = h0;
      }
    }
    // pass 1: blades 8..15 -> HT1 (overlays XA; barrier first)
    {
      f32x4 acc[8];
      #pragma unroll
      for (int j = 0; j < 8; ++j) acc[j] = f32x4{0.f,0.f,0.f,0.f};
      ga_half<1>(acc, WB, lds, nt, lane);
      __syncthreads();                 // all XA reads complete
      #pragma unroll
      for (int r = 0; r < 4; ++r) {
        const int p = pg*4 + r;
        bf16x8 h1;
        #pragma unroll
        for (int j = 0; j < 8; ++j) h1[j] = (__bf16)acc[j][r];
        *(bf16x8*)(lds + htaddr(p, o)) = h1;
      }
    }
  }
  __syncthreads();

  // ---------------- GP + JOIN into registers ----------------
  float gpo[16], jno[16];
  {
    const int p2 = tid >> 5, ch = tid & 31;
    float L[16], R[16];
    auto ldrow = [&](int row, float* X){
      bf16x8 a = *(const bf16x8*)(lds + HT0_OFF + htaddr(p2, row));
      bf16x8 b = *(const bf16x8*)(lds + htaddr(p2, row));
      #pragma unroll
      for (int t = 0; t < 8; ++t) { X[t] = (float)a[t]; X[8+t] = (float)b[t]; }
    };
    ldrow(ch, L); ldrow(32 + ch, R);
    #pragma unroll
    for (int j = 0; j < 16; ++j) gpo[j] = 0.0f;
    #pragma unroll
    for (int n = 0; n < 192; ++n)
      gpo[ga::GPt.e[n].k] = fmaf(ga::GPt.e[n].s * L[ga::GPt.e[n].i], R[ga::GPt.e[n].j], gpo[ga::GPt.e[n].k]);
    ldrow(64 + ch, L); ldrow(96 + ch, R);
    #pragma unroll
    for (int j = 0; j < 16; ++j) jno[j] = 0.0f;
    #pragma unroll
    for (int n = 0; n < 81; ++n)
      jno[ga::JNt.e[n].k] = fmaf(ga::JNt.e[n].s * L[ga::JNt.e[n].i], R[ga::JNt.e[n].j], jno[ga::JNt.e[n].k]);
  }
  __syncthreads();                     // HT reads complete -> overlay XA/C0

  { // write hidden -> XA bf16 [16j][16p][64c] + C0
    const int p2 = tid >> 5, ch = tid & 31;
    #pragma unroll
    for (int j = 0; j < 16; ++j) {
      *(__bf16*)(lds + XA_OFF + (((j<<4)+p2)<<7) + swz(p2, 2*ch))      = (__bf16)gpo[j];
      *(__bf16*)(lds + XA_OFF + (((j<<4)+p2)<<7) + swz(p2, 2*(32+ch))) = (__bf16)jno[j];
    }
    *(__bf16*)(lds + C0_OFF + (p2<<7) + swz(p2, 2*ch))      = (__bf16)gpo[0];
    *(__bf16*)(lds + C0_OFF + (p2<<7) + swz(p2, 2*(32+ch))) = (__bf16)jno[0];
  }
  __syncthreads();

  // ---------------- phases B, C, D (hi-only) ----------------
  const int w = wv & 3, jh = wv >> 2;
  float* REDEQ = (float*)(lds + RED_OFF);        // [8][16]
  float* REDS  = REDEQ + 128;
  float* REDQ  = REDEQ + 256;
  float* GT    = (float*)(lds + GT_OFF);         // [16p][64o]

  #pragma unroll 1
  for (int stage = 0; stage < 2; ++stage) {
    const int mvb   = stage == 0 ? FB_MVB    : FB_MVC;
    const int s2mvb = stage == 0 ? FB_S2MV_B : FB_S2MV_C;
    const int s2sb  = stage == 0 ? FB_S2S_B  : FB_S2S_C;
    const int ms2sb = stage == 0 ? FB_MS2S_B : FB_MS2S_C;
    const int sab   = stage == 0 ? SA_OFF    : T1_OFF;
    const int tdst  = stage == 0 ? T1_OFF    : T2_OFF;
    const float* b_mv = stage == 0 ? gbo_b_mv : l1_b_mv;
    const float* b_s  = stage == 0 ? gbo_b_s  : l1_b_s;
    const int nt0 = 4*w + 2*jh;

    f32x4 acc[8], fac[2];
    #pragma unroll
    for (int j = 0; j < 8; ++j) acc[j] = f32x4{0.f,0.f,0.f,0.f};
    fac[0] = f32x4{0.f,0.f,0.f,0.f}; fac[1] = f32x4{0.f,0.f,0.f,0.f};

    if (jh == 0) mv_half<0>(acc, WB, lds, mvb, w, lane);
    else         mv_half<1>(acc, WB, lds, mvb, w, lane);

    if (stage == 0) {
      if (jh == 0) s_gemm<4,8>(acc[0], WB, lds, sab, s2mvb + w*2048, lane);
      #pragma unroll
      for (int i = 0; i < 2; ++i) {
        s_gemm<4,8>(fac[i], WB, lds, sab, s2sb + (nt0+i)*2048, lane);
        s_gemm<2,7>(fac[i], WB, lds, C0_OFF, ms2sb + (nt0+i)*1024, lane);
      }
    } else {
      if (jh == 0) s_gemm<8,9>(acc[0], WB, lds, sab, s2mvb + w*4096, lane);
      #pragma unroll
      for (int i = 0; i < 2; ++i) {
        s_gemm<8,9>(fac[i], WB, lds, sab, s2sb + (nt0+i)*4096, lane);
        s_gemm<2,7>(fac[i], WB, lds, C0_OFF, ms2sb + (nt0+i)*1024, lane);
      }
    }
    __syncthreads();

    if (jh == 0) {
      const float bm = b_mv[16*w + ol];
      #pragma unroll
      for (int r = 0; r < 4; ++r) acc[0][r] += bm;
    }
    #pragma unroll
    for (int i = 0; i < 2; ++i) {
      const float bs = b_s[16*(nt0+i) + ol];
      #pragma unroll
      for (int r = 0; r < 4; ++r) fac[i][r] += bs;
    }
    float sq[4], sm[4], s2[4];
    #pragma unroll
    for (int r = 0; r < 4; ++r) {
      sq[r] = (jh == 0)
        ? acc[0][r]*acc[0][r] + acc[2][r]*acc[2][r] + acc[3][r]*acc[3][r] + acc[4][r]*acc[4][r]
        : acc[0][r]*acc[0][r] + acc[1][r]*acc[1][r] + acc[2][r]*acc[2][r] + acc[6][r]*acc[6][r];
      sm[r] = fac[0][r] + fac[1][r];
      s2[r] = fac[0][r]*fac[0][r] + fac[1][r]*fac[1][r];
    }
    #pragma unroll
    for (int m = 1; m < 16; m <<= 1) {
      #pragma unroll
      for (int r = 0; r < 4; ++r) {
        sq[r] += __shfl_xor(sq[r], m);
        sm[r] += __shfl_xor(sm[r], m);
        s2[r] += __shfl_xor(s2[r], m);
      }
    }
    if (ol == 0) {
      #pragma unroll
      for (int r = 0; r < 4; ++r) {
        const int p = pg*4 + r;
        REDEQ[wv*16 + p] = sq[r]; REDS[wv*16 + p] = sm[r]; REDQ[wv*16 + p] = s2[r];
      }
    }
    __syncthreads();

    float rs[4], mu[4], rstd[4];
    #pragma unroll
    for (int r = 0; r < 4; ++r) {
      const int p = pg*4 + r;
      float te = 0.f, ts = 0.f, tq = 0.f;
      #pragma unroll
      for (int v2 = 0; v2 < 8; ++v2) { te += REDEQ[v2*16+p]; ts += REDS[v2*16+p]; tq += REDQ[v2*16+p]; }
      rs[r]   = 1.0f / sqrtf(fmaxf(te * (1.0f/64.0f), 0.01f));
      mu[r]   = ts * (1.0f/256.0f);
      rstd[r] = rsqrtf(tq * (1.0f/256.0f) - mu[r]*mu[r] + 1e-5f);
    }
    #pragma unroll
    for (int i = 0; i < 2; ++i) {
      #pragma unroll
      for (int r = 0; r < 4; ++r) {
        const int p = pg*4 + r, op = 16*(nt0+i) + ol;
        *(__bf16*)(lds + tdst + (p << 9) + swz(p, 2*op)) =
            (__bf16)gelu_t((fac[i][r] - mu[r]) * rstd[r]);
      }
    }
    if (jh == 0) {
      const int cnew = 16*w + ol;
      #pragma unroll
      for (int r = 0; r < 4; ++r) {
        const int p = pg*4 + r;
        const float a0n = acc[0][r] * rs[r];
        const float g   = gelu_t(a0n);
        GT[p*64 + cnew] = g;
        *(__bf16*)(lds + C0_OFF + (p<<7) + swz(p, 2*cnew)) = (__bf16)(g * a0n);
      }
    }
    __syncthreads();

    {
      const int cnew = 16*w + ol;
      float f[4];
      #pragma unroll
      for (int r = 0; r < 4; ++r) f[r] = rs[r] * GT[(pg*4+r)*64 + cnew];
      #pragma unroll
      for (int jl = 0; jl < 8; ++jl) {
        const int j = jh*8 + jl;
        #pragma unroll
        for (int r = 0; r < 4; ++r) {
          const int p = pg*4 + r;
          *(__bf16*)(lds + XA_OFF + (((j<<4)+p)<<7) + swz(p, 2*cnew)) = (__bf16)(acc[jl][r] * f[r]);
        }
      }
    }
    __syncthreads();
  }

  { // ---------------- stage D ----------------
    f32x4 acc[8], fac2;
    #pragma unroll
    for (int j = 0; j < 8; ++j) acc[j] = f32x4{0.f,0.f,0.f,0.f};
    fac2 = f32x4{0.f,0.f,0.f,0.f};

    if (jh == 0) mv_half<0>(acc, WB, lds, FB_MVD, w, lane);
    else         mv_half<1>(acc, WB, lds, FB_MVD, w, lane);
    if (jh == 0) s_gemm<8,9>(acc[0], WB, lds, T2_OFF, FB_S2MV_D + w*4096, lane);
    const int ntd = w + 4*jh;
    s_gemm<8,9>(fac2, WB, lds, T2_OFF, FB_S2S_D + ntd*4096, lane);
    s_gemm<2,7>(fac2, WB, lds, C0_OFF, FB_MS2S_D + ntd*1024, lane);

    if (jh == 0) {
      const float bm = l2_b_mv[16*w + ol];
      #pragma unroll
      for (int r = 0; r < 4; ++r) acc[0][r] += bm;
    }
    #pragma unroll
    for (int r = 0; r < 4; ++r) {
      const int p = pg*4 + r;
      float* dst = out + ((size_t)(n0 + p)*64 + 16*w + ol)*16 + jh*8;
      *(float4*)(dst+0) = make_float4(acc[0][r], acc[1][r], acc[2][r], acc[3][r]);
      *(float4*)(dst+4) = make_float4(acc[4][r], acc[5][r], acc[6][r], acc[7][r]);
    }
    {
      const int od = 16*ntd + ol;
      const float bs = l2_b_s[od];
      #pragma unroll
      for (int r = 0; r < 4; ++r) {
        const int p = pg*4 + r;
        out[SOFF + (size_t)(n0 + p)*128 + od] = fac2[r] + bs;
      }
    }
  }
}

// ============================ host launch ============================
extern "C" void kernel_launch(void* const* d_in, const int* in_sizes, int n_in,
                              void* d_out, int out_size, void* d_ws, size_t ws_size,
                              hipStream_t stream) {
  const float* xin          = (const float*)d_in[0];
  const float* sinp         = (const float*)d_in[1];
  const float* gb_w_mv      = (const float*)d_in[2];
  const float* gb_w_s2mv    = (const float*)d_in[3];
  const float* gb_b_mv      = (const float*)d_in[4];
  const float* gbo_w_mv     = (const float*)d_in[5];
  const float* gbo_w_s2mv   = (const float*)d_in[6];
  const float* gbo_b_mv     = (const float*)d_in[7];
  const float* gbo_w_mvs2s  = (const float*)d_in[8];
  const float* gbo_w_s2s    = (const float*)d_in[9];
  const float* gbo_b_s      = (const float*)d_in[10];
  const float* l1_w_mv      = (const float*)d_in[11];
  const float* l1_w_s2mv    = (const float*)d_in[12];
  const float* l1_b_mv      = (const float*)d_in[13];
  const float* l1_w_mvs2s   = (const float*)d_in[14];
  const float* l1_w_s2s     = (const float*)d_in[15];
  const float* l1_b_s       = (const float*)d_in[16];
  const float* l2_w_mv      = (const float*)d_in[17];
  const float* l2_w_s2mv    = (const float*)d_in[18];
  const float* l2_b_mv      = (const float*)d_in[19];
  const float* l2_w_mvs2s   = (const float*)d_in[20];
  const float* l2_w_s2s     = (const float*)d_in[21];
  const float* l2_b_s       = (const float*)d_in[22];
  unsigned short* WBu = (unsigned short*)d_ws;
  float* out = (float*)d_out;

  prep_bf<<<(TOT_BF + 255) / 256, 256, 0, stream>>>(
      gbo_w_mv, gbo_w_s2mv, gbo_w_mvs2s, gbo_w_s2s,
      l1_w_mv, l1_w_s2mv, l1_w_mvs2s, l1_w_s2s,
      l2_w_mv, l2_w_s2mv, l2_w_mvs2s, l2_w_s2s, WBu);

  prep_ga<<<(SA_TOT + 255) / 256, 256, 0, stream>>>(gb_w_mv, gb_w_s2mv, WBu);

  fused_all<<<NPTS / 16, 512, 0, stream>>>(
      xin, sinp, gb_b_mv, gbo_b_mv, gbo_b_s, l1_b_mv, l1_b_s,
      l2_b_mv, l2_b_s, WBu, out);
}